// Round 3
// baseline (688.275 us; speedup 1.0000x reference)
//
#include <hip/hip_runtime.h>
#include <stdint.h>

typedef __bf16 bf16;
typedef __bf16 bf16x8 __attribute__((ext_vector_type(8)));
typedef __bf16 bf16x4 __attribute__((ext_vector_type(4)));
typedef float f32x4 __attribute__((ext_vector_type(4)));

#define DEVFN static __device__ __forceinline__

constexpr int S = 2048, Hdim = 2048, NH = 16, NKV = 4, HD = 128, RHD = 64, QC = 1536, KVC = 512;
constexpr int QKD = HD + RHD;                 // 192
constexpr int DN = 2112;                      // merged down-proj width: QC + KVC + RHD
constexpr float RMS_EPS = 1e-6f;
constexpr float ATT_SCALE = 0.07216878364870323f;  // 1/sqrt(192)

// ---------------- reductions ----------------
DEVFN float wave_sum(float v) {
#pragma unroll
  for (int o = 32; o > 0; o >>= 1) v += __shfl_xor(v, o, 64);
  return v;
}
DEVFN float wave_max(float v) {
#pragma unroll
  for (int o = 32; o > 0; o >>= 1) v = fmaxf(v, __shfl_xor(v, o, 64));
  return v;
}
DEVFN float block_sum(float v) {
  __shared__ float red_s[4];
  v = wave_sum(v);
  int lane = threadIdx.x & 63, wid = threadIdx.x >> 6;
  if (lane == 0) red_s[wid] = v;
  __syncthreads();
  v = red_s[0] + red_s[1] + red_s[2] + red_s[3];
  __syncthreads();
  return v;
}

// ---------------- async global->LDS (16B per lane) ----------------
DEVFN void gload16(const bf16* g, bf16* l) {
  __builtin_amdgcn_global_load_lds(
      (const __attribute__((address_space(1))) uint32_t*)g,
      (__attribute__((address_space(3))) uint32_t*)l, 16, 0, 0);
}

// ---------------- async GEMM core (m97 structure): C = A[M,K] * Bt[N,K]^T ---
template <typename OT>
DEVFN void gemm_core_async(const bf16* __restrict__ A, const bf16* __restrict__ Bt,
                           OT* __restrict__ C, int N, int lda, int ldb, int ldc,
                           int m0, int n0, float scale, int kend) {
  __shared__ alignas(16) bf16 As[128 * 32];
  __shared__ alignas(16) bf16 Bs[128 * 32];
  const int t = threadIdx.x;
  const int lane = t & 63;
  const int wm = ((t >> 7) & 1) * 64;
  const int wn = ((t >> 6) & 1) * 64;
  const int lr = lane & 15;
  const int lk = (lane >> 4) * 8;
  const int srow = t >> 2;
  const int scol = (t & 3) * 8;
  const bf16* Ab = A + (size_t)(m0 + srow) * lda + scol;
  const bf16* Bb = Bt + (size_t)(n0 + srow) * ldb + scol;
  bf16* Al = As + t * 8;
  bf16* Bl = Bs + t * 8;

  f32x4 acc[4][4];
#pragma unroll
  for (int i = 0; i < 4; i++)
#pragma unroll
    for (int j = 0; j < 4; j++) { f32x4 z = {0.f, 0.f, 0.f, 0.f}; acc[i][j] = z; }

  for (int kk = 0; kk < kend; kk += 32) {
    gload16(Ab + kk, Al);
    gload16(Ab + (size_t)64 * lda + kk, Al + 2048);
    gload16(Bb + kk, Bl);
    gload16(Bb + (size_t)64 * ldb + kk, Bl + 2048);
    __syncthreads();
    bf16x8 a[4], b[4];
#pragma unroll
    for (int i = 0; i < 4; i++)
      a[i] = *reinterpret_cast<const bf16x8*>(&As[(wm + i * 16 + lr) * 32 + lk]);
#pragma unroll
    for (int i = 0; i < 4; i++)
      b[i] = *reinterpret_cast<const bf16x8*>(&Bs[(wn + i * 16 + lr) * 32 + lk]);
#pragma unroll
    for (int i = 0; i < 4; i++)
#pragma unroll
      for (int j = 0; j < 4; j++)
        acc[i][j] = __builtin_amdgcn_mfma_f32_16x16x32_bf16(a[i], b[j], acc[i][j], 0, 0, 0);
    __syncthreads();
  }
  const int orow = (lane >> 4) * 4;
#pragma unroll
  for (int i = 0; i < 4; i++) {
#pragma unroll
    for (int j = 0; j < 4; j++) {
      int col = n0 + wn + j * 16 + lr;
      if (col < N) {
#pragma unroll
        for (int q = 0; q < 4; q++) {
          int row = m0 + wm + i * 16 + orow + q;
          C[(size_t)row * ldc + col] = (OT)(acc[i][j][q] * scale);
        }
      }
    }
  }
}

// bijective XCD-aware swizzle of linear block id (8 XCDs)
DEVFN void xcd_map(int& bx, int& by) {
  int nx = gridDim.x;
  int nwg = nx * gridDim.y;
  int id = blockIdx.y * nx + blockIdx.x;
  int q = nwg >> 3, r = nwg & 7;
  int xcd = id & 7, i = id >> 3;
  int swz = (xcd < r) ? (xcd * (q + 1) + i) : (r * (q + 1) + (xcd - r) * q + i);
  bx = swz % nx;
  by = swz / nx;
}

template <typename OT>
__global__ __launch_bounds__(256) void gemm_nt(const bf16* __restrict__ A, const bf16* __restrict__ Bt,
                                               OT* __restrict__ C, int N, int K, int lda,
                                               int ldb, int ldc, float scale) {
  int bx, by;
  xcd_map(bx, by);
  gemm_core_async<OT>(A, Bt, C, N, lda, ldb, ldc, by * 128, bx * 128, scale, K);
}

// scores for one KV group (4 heads), causal block-skip
__global__ __launch_bounds__(256) void gemm_scores(const bf16* __restrict__ qpack,
                                                   const bf16* __restrict__ kpack,
                                                   float* __restrict__ attn, int g) {
  int h = g * 4 + blockIdx.z;
  int m0 = blockIdx.y * 128, n0 = blockIdx.x * 128;
  if (n0 > m0) return;
  gemm_core_async<float>(qpack + (size_t)h * S * QKD, kpack + (size_t)g * S * QKD,
                         attn + (size_t)h * S * S, S, QKD, QKD, S, m0, n0, ATT_SCALE, QKD);
}

// ---------------- reg-staged PV (fp32 A) ----------------
DEVFN void stage8f(bf16* __restrict__ lds, const float* __restrict__ G, int grow, int gcol,
                   int ld, int lrow, int lcol) {
  const float* p = G + (size_t)grow * ld + gcol;
  float4 f0 = *reinterpret_cast<const float4*>(p);
  float4 f1 = *reinterpret_cast<const float4*>(p + 4);
  bf16x8 v;
  v[0] = (bf16)f0.x; v[1] = (bf16)f0.y; v[2] = (bf16)f0.z; v[3] = (bf16)f0.w;
  v[4] = (bf16)f1.x; v[5] = (bf16)f1.y; v[6] = (bf16)f1.z; v[7] = (bf16)f1.w;
  *reinterpret_cast<bf16x8*>(&lds[lrow * 40 + lcol]) = v;
}
DEVFN void stage8b(bf16* __restrict__ lds, const bf16* __restrict__ G, int grow, int gcol,
                   int ld, int lrow, int lcol) {
  *reinterpret_cast<bf16x8*>(&lds[lrow * 40 + lcol]) =
      *reinterpret_cast<const bf16x8*>(G + (size_t)grow * ld + gcol);
}

__global__ __launch_bounds__(256) void gemm_pv(const float* __restrict__ attn,
                                               const bf16* __restrict__ vt,
                                               bf16* __restrict__ ctxb, int g) {
  int h = g * 4 + blockIdx.z;
  const float* A = attn + (size_t)h * S * S;
  const bf16* Bt = vt + (size_t)g * HD * S;
  bf16* C = ctxb + h * HD;
  const int m0 = blockIdx.y * 128;
  const int kend = m0 + 128;  // causal
  __shared__ alignas(16) bf16 As[128 * 40];
  __shared__ alignas(16) bf16 Bs[128 * 40];
  const int t = threadIdx.x;
  const int lane = t & 63;
  const int wm = ((t >> 7) & 1) * 64;
  const int wn = ((t >> 6) & 1) * 64;
  const int lr = lane & 15;
  const int lk = (lane >> 4) * 8;
  const int r0 = t >> 2;
  const int c0 = (t & 3) * 8;
  f32x4 acc[4][4];
#pragma unroll
  for (int i = 0; i < 4; i++)
#pragma unroll
    for (int j = 0; j < 4; j++) { f32x4 z = {0.f, 0.f, 0.f, 0.f}; acc[i][j] = z; }

  for (int kk = 0; kk < kend; kk += 32) {
    stage8f(As, A, m0 + r0, kk + c0, S, r0, c0);
    stage8f(As, A, m0 + r0 + 64, kk + c0, S, r0 + 64, c0);
    stage8b(Bs, Bt, r0, kk + c0, S, r0, c0);
    stage8b(Bs, Bt, r0 + 64, kk + c0, S, r0 + 64, c0);
    __syncthreads();
    bf16x8 a[4], b[4];
#pragma unroll
    for (int i = 0; i < 4; i++)
      a[i] = *reinterpret_cast<const bf16x8*>(&As[(wm + i * 16 + lr) * 40 + lk]);
#pragma unroll
    for (int i = 0; i < 4; i++)
      b[i] = *reinterpret_cast<const bf16x8*>(&Bs[(wn + i * 16 + lr) * 40 + lk]);
#pragma unroll
    for (int i = 0; i < 4; i++)
#pragma unroll
      for (int j = 0; j < 4; j++)
        acc[i][j] = __builtin_amdgcn_mfma_f32_16x16x32_bf16(a[i], b[j], acc[i][j], 0, 0, 0);
    __syncthreads();
  }
  const int orow = (lane >> 4) * 4;
#pragma unroll
  for (int i = 0; i < 4; i++) {
#pragma unroll
    for (int j = 0; j < 4; j++) {
      int col = wn + j * 16 + lr;
#pragma unroll
      for (int q = 0; q < 4; q++) {
        int row = m0 + wm + i * 16 + orow + q;
        C[(size_t)row * Hdim + col] = (bf16)acc[i][j][q];
      }
    }
  }
}

// ---------------- elementwise / reshape ----------------
__global__ __launch_bounds__(256) void cast_f32_bf16(const float* __restrict__ in,
                                                     bf16* __restrict__ out, int n8) {
  int i = blockIdx.x * 256 + threadIdx.x;
  if (i >= n8) return;
  float4 f0 = *reinterpret_cast<const float4*>(in + (size_t)i * 8);
  float4 f1 = *reinterpret_cast<const float4*>(in + (size_t)i * 8 + 4);
  bf16x8 v;
  v[0] = (bf16)f0.x; v[1] = (bf16)f0.y; v[2] = (bf16)f0.z; v[3] = (bf16)f0.w;
  v[4] = (bf16)f1.x; v[5] = (bf16)f1.y; v[6] = (bf16)f1.z; v[7] = (bf16)f1.w;
  *reinterpret_cast<bf16x8*>(out + (size_t)i * 8) = v;
}

// batched fp32 [R][C] -> bf16 [C][R] transposes (8 jobs, one dispatch)
struct TJobs {
  const float* src[8];
  bf16* dst[8];
  int R[8], C[8], tiles[8];
};

__global__ __launch_bounds__(256) void transpose_batch(TJobs J) {
  int tile = blockIdx.x;
  int j = 0;
  while (tile >= J.tiles[j]) { tile -= J.tiles[j]; ++j; }
  const int C = J.C[j], R = J.R[j];
  int tcn = C >> 5;
  int rb = (tile / tcn) * 32, cb = (tile % tcn) * 32;
  const float* in = J.src[j];
  bf16* out = J.dst[j];
  __shared__ float tl[32][33];
  int tx = threadIdx.x, ty = threadIdx.y;
#pragma unroll
  for (int q = 0; q < 32; q += 8)
    tl[ty + q][tx] = in[(size_t)(rb + ty + q) * C + cb + tx];
  __syncthreads();
#pragma unroll
  for (int q = 0; q < 32; q += 8)
    out[(size_t)(cb + ty + q) * R + rb + tx] = (bf16)tl[tx][ty + q];
}

// bf16 [R][C] (ld=ild) -> bf16 [C][R] (ld=old_)
__global__ __launch_bounds__(256) void transpose_b16(const bf16* __restrict__ in,
                                                     bf16* __restrict__ out, int R, int ild, int old_) {
  __shared__ float tl[32][33];
  int tx = threadIdx.x, ty = threadIdx.y;
  int cb = blockIdx.x * 32, rb = blockIdx.y * 32;
#pragma unroll
  for (int q = 0; q < 32; q += 8)
    tl[ty + q][tx] = (float)in[(size_t)(rb + ty + q) * ild + cb + tx];
  __syncthreads();
#pragma unroll
  for (int q = 0; q < 32; q += 8)
    out[(size_t)(cb + ty + q) * old_ + rb + tx] = (bf16)tl[tx][ty + q];
}

// fused RMSNorm for cq (y==0) and ckv (y==1) reading merged dproj
__global__ __launch_bounds__(256) void rmsnorm_fused(const float* __restrict__ dproj,
                                                     const float* __restrict__ qw,
                                                     const float* __restrict__ kw,
                                                     bf16* __restrict__ cqb,
                                                     bf16* __restrict__ ckvb) {
  int row = blockIdx.x;
  bool isq = (blockIdx.y == 0);
  int C = isq ? QC : KVC;
  const float* p = dproj + (size_t)row * DN + (isq ? 0 : QC);
  const float* w = isq ? qw : kw;
  bf16* out = (isq ? cqb : ckvb) + (size_t)row * C;
  float ss = 0.f;
  for (int i = threadIdx.x * 4; i < C; i += 1024) {
    float4 v = *reinterpret_cast<const float4*>(p + i);
    ss += v.x * v.x + v.y * v.y + v.z * v.z + v.w * v.w;
  }
  ss = block_sum(ss);
  float r = rsqrtf(ss / (float)C + RMS_EPS);
  for (int i = threadIdx.x * 4; i < C; i += 1024) {
    float4 v = *reinterpret_cast<const float4*>(p + i);
    float4 g = *reinterpret_cast<const float4*>(w + i);
    bf16x4 o;
    o[0] = (bf16)(v.x * r * g.x); o[1] = (bf16)(v.y * r * g.y);
    o[2] = (bf16)(v.z * r * g.z); o[3] = (bf16)(v.w * r * g.w);
    *reinterpret_cast<bf16x4*>(out + i) = o;
  }
}

// fused: pack qc slice of up1 into qpack + RoPE'd qr into qpack[...,128:]
__global__ __launch_bounds__(256) void build_qpack(const bf16* __restrict__ up1,
                                                   const float* __restrict__ cosp,
                                                   const float* __restrict__ sinp,
                                                   bf16* __restrict__ qpack) {
  int idx = blockIdx.x * 256 + threadIdx.x;
  const int P = NH * S * 16;  // 8-elem chunks of qc
  if (idx < P) {
    int d8 = idx & 15, s = (idx >> 4) & (S - 1), h = idx >> 15;
    int4 v = *reinterpret_cast<const int4*>(up1 + (size_t)s * 3072 + h * HD + d8 * 8);
    *reinterpret_cast<int4*>(qpack + ((size_t)h * S + s) * QKD + d8 * 8) = v;
  } else {
    int j = idx - P;
    int d0 = (j & 7) * 8, s = (j >> 3) & (S - 1), h = j >> 14;
    const bf16* xr = up1 + (size_t)s * 3072 + 2048 + h * RHD;
    bf16x8 xa = *reinterpret_cast<const bf16x8*>(xr + d0);
    bf16x8 xb = *reinterpret_cast<const bf16x8*>(xr + (d0 ^ 32));
    float sign = (d0 < 32) ? -1.f : 1.f;
    const float* cr = cosp + s * RHD + d0;
    const float* sr = sinp + s * RHD + d0;
    bf16x8 o;
#pragma unroll
    for (int i = 0; i < 8; i++)
      o[i] = (bf16)((float)xa[i] * cr[i] + sign * (float)xb[i] * sr[i]);
    *reinterpret_cast<bf16x8*>(qpack + ((size_t)h * S + s) * QKD + HD + d0) = o;
  }
}

// fused: pack kc slice of up2 into kpack + RoPE'd kr (from dproj col 2048) into all groups
__global__ __launch_bounds__(256) void build_kpack(const bf16* __restrict__ up2,
                                                   const float* __restrict__ dproj,
                                                   const float* __restrict__ cosp,
                                                   const float* __restrict__ sinp,
                                                   bf16* __restrict__ kpack) {
  int idx = blockIdx.x * 256 + threadIdx.x;
  const int P = NKV * S * 16;
  if (idx < P) {
    int d8 = idx & 15, s = (idx >> 4) & (S - 1), g = idx >> 15;
    int4 v = *reinterpret_cast<const int4*>(up2 + (size_t)s * 1024 + g * HD + d8 * 8);
    *reinterpret_cast<int4*>(kpack + ((size_t)g * S + s) * QKD + d8 * 8) = v;
  } else {
    int j = idx - P;
    int d0 = (j & 7) * 8, s = j >> 3;
    const float* xr = dproj + (size_t)s * DN + 2048;
    float4 a0 = *reinterpret_cast<const float4*>(xr + d0);
    float4 a1 = *reinterpret_cast<const float4*>(xr + d0 + 4);
    float4 b0 = *reinterpret_cast<const float4*>(xr + (d0 ^ 32));
    float4 b1 = *reinterpret_cast<const float4*>(xr + (d0 ^ 32) + 4);
    float sign = (d0 < 32) ? -1.f : 1.f;
    const float* cr = cosp + s * RHD + d0;
    const float* sr = sinp + s * RHD + d0;
    float xa[8] = {a0.x, a0.y, a0.z, a0.w, a1.x, a1.y, a1.z, a1.w};
    float xb[8] = {b0.x, b0.y, b0.z, b0.w, b1.x, b1.y, b1.z, b1.w};
    bf16x8 o;
#pragma unroll
    for (int i = 0; i < 8; i++)
      o[i] = (bf16)(xa[i] * cr[i] + sign * xb[i] * sr[i]);
#pragma unroll
    for (int g = 0; g < NKV; g++)
      *reinterpret_cast<bf16x8*>(kpack + ((size_t)g * S + s) * QKD + HD + d0) = o;
  }
}

// wave-per-row causal softmax, no LDS, no block syncs; zeros masked tail
__global__ __launch_bounds__(256) void softmax_rows(float* __restrict__ attn, int h0) {
  int wid = threadIdx.x >> 6, lane = threadIdx.x & 63;
  int s = blockIdx.x * 4 + wid;
  int h = h0 + blockIdx.y;
  float* row = attn + ((size_t)h * S + s) * S;
  const int n = s + 1;
  const int nchunks = (n + 255) >> 8;
  float4 ev[8];
  float m = -1e30f;
  for (int c = 0; c < nchunks; c++) {
    int i = c * 256 + lane * 4;
    float4 v = make_float4(-1e30f, -1e30f, -1e30f, -1e30f);
    if (i + 4 <= n) v = *reinterpret_cast<const float4*>(row + i);
    else {
      if (i < n) v.x = row[i];
      if (i + 1 < n) v.y = row[i + 1];
      if (i + 2 < n) v.z = row[i + 2];
    }
    ev[c] = v;
    m = fmaxf(m, fmaxf(fmaxf(v.x, v.y), fmaxf(v.z, v.w)));
  }
  m = wave_max(m);
  float l = 0.f;
  for (int c = 0; c < nchunks; c++) {
    float4 v = ev[c];
    v.x = __expf(v.x - m); v.y = __expf(v.y - m);
    v.z = __expf(v.z - m); v.w = __expf(v.w - m);
    ev[c] = v;
    l += v.x + v.y + v.z + v.w;
  }
  l = wave_sum(l);
  float inv = 1.0f / l;
  for (int c = 0; c < nchunks; c++) {
    int i = c * 256 + lane * 4;
    float4 v = ev[c];
    v.x *= inv; v.y *= inv; v.z *= inv; v.w *= inv;
    if (i + 4 <= n) *reinterpret_cast<float4*>(row + i) = v;
    else {
      if (i < n) row[i] = v.x;
      if (i + 1 < n) row[i + 1] = v.y;
      if (i + 2 < n) row[i + 2] = v.z;
    }
  }
  // zero masked tail [n, S)
  int z0 = (n + 3) & ~3;
  if (lane < z0 - n) row[n + lane] = 0.f;
  const float4 zz = make_float4(0.f, 0.f, 0.f, 0.f);
  for (int i = z0 + lane * 4; i < S; i += 256) *reinterpret_cast<float4*>(row + i) = zz;
}

// ---------------- launcher ----------------
extern "C" void kernel_launch(void* const* d_in, const int* in_sizes, int n_in, void* d_out,
                              int out_size, void* d_ws, size_t ws_size, hipStream_t stream) {
  const float* Xf = (const float*)d_in[0];
  const float* cosp = (const float*)d_in[1];
  const float* sinp = (const float*)d_in[2];
  const float* w_down_q = (const float*)d_in[4];
  const float* w_up_q = (const float*)d_in[5];
  const float* w_qr = (const float*)d_in[6];
  const float* w_down_kv = (const float*)d_in[7];
  const float* w_up_k = (const float*)d_in[8];
  const float* w_up_v = (const float*)d_in[9];
  const float* w_kr = (const float*)d_in[10];
  const float* w_o = (const float*)d_in[11];
  const float* q_norm_w = (const float*)d_in[12];
  const float* k_norm_w = (const float*)d_in[13];

  float* out0 = (float*)d_out;
  float* attn = out0 + (size_t)S * Hdim;

  char* base = (char*)d_ws;
  size_t off = 0;
  auto carve = [&](size_t bytes) -> void* {
    void* p = base + off;
    off += (bytes + 255) & ~(size_t)255;
    return p;
  };
  bf16* Xb      = (bf16*)carve((size_t)S * Hdim * 2);
  bf16* wt_down = (bf16*)carve((size_t)2176 * 2048 * 2);  // [2112(+pad)][2048]
  bf16* wt_up1  = (bf16*)carve((size_t)3072 * QC * 2);    // [3072][1536]
  bf16* wt_up2  = (bf16*)carve((size_t)1024 * KVC * 2);   // [1024][512]
  bf16* wt_o    = (bf16*)carve((size_t)Hdim * Hdim * 2);
  float* dproj  = (float*)carve((size_t)S * DN * 4);      // [2048][2112]
  bf16* cqb     = (bf16*)carve((size_t)S * QC * 2);
  bf16* ckvb    = (bf16*)carve((size_t)S * KVC * 2);
  bf16* up1     = (bf16*)carve((size_t)S * 3072 * 2);     // [s][qc 0:2048 | qr 2048:3072]
  bf16* up2     = (bf16*)carve((size_t)S * 1024 * 2);     // [s][kc 0:512 | v 512:1024]
  bf16* qpack   = (bf16*)carve((size_t)NH * S * QKD * 2);
  bf16* kpack   = (bf16*)carve((size_t)NKV * S * QKD * 2);
  bf16* vt      = (bf16*)carve((size_t)NKV * HD * S * 2);
  bf16* ctxb    = (bf16*)carve((size_t)S * Hdim * 2);
  (void)in_sizes; (void)n_in; (void)out_size; (void)ws_size;

  dim3 tb(32, 8);
  cast_f32_bf16<<<S * Hdim / 8 / 256, 256, 0, stream>>>(Xf, Xb, S * Hdim / 8);

  TJobs J;
  const float* srcs[8] = {w_down_q, w_down_kv, w_kr, w_up_q, w_qr, w_up_k, w_up_v, w_o};
  bf16* dsts[8] = {wt_down, wt_down + (size_t)QC * 2048, wt_down + (size_t)2048 * 2048,
                   wt_up1, wt_up1 + (size_t)2048 * QC, wt_up2, wt_up2 + (size_t)512 * KVC, wt_o};
  int Rs[8] = {2048, 2048, 2048, 1536, 1536, 512, 512, 2048};
  int Cs[8] = {1536, 512, 64, 2048, 1024, 512, 512, 2048};
  int total_tiles = 0;
  for (int j = 0; j < 8; j++) {
    J.src[j] = srcs[j]; J.dst[j] = dsts[j]; J.R[j] = Rs[j]; J.C[j] = Cs[j];
    J.tiles[j] = (Rs[j] / 32) * (Cs[j] / 32);
    total_tiles += J.tiles[j];
  }
  transpose_batch<<<total_tiles, tb, 0, stream>>>(J);

  // merged down projection: [S][2112] = Xb @ [wdq | wdkv | wkr]
  gemm_nt<float><<<dim3(17, 16), 256, 0, stream>>>(Xb, wt_down, dproj, DN, Hdim, Hdim, Hdim, DN, 1.f);
  rmsnorm_fused<<<dim3(S, 2), 256, 0, stream>>>(dproj, q_norm_w, k_norm_w, cqb, ckvb);

  // merged up projections
  gemm_nt<bf16><<<dim3(24, 16), 256, 0, stream>>>(cqb, wt_up1, up1, 3072, QC, QC, QC, 3072, 1.f);
  gemm_nt<bf16><<<dim3(8, 16), 256, 0, stream>>>(ckvb, wt_up2, up2, 1024, KVC, KVC, KVC, 1024, 1.f);

  build_qpack<<<(NH * S * 16 + NH * S * 8) / 256, 256, 0, stream>>>(up1, cosp, sinp, qpack);
  build_kpack<<<(NKV * S * 16 + S * 8) / 256, 256, 0, stream>>>(up2, dproj, cosp, sinp, kpack);
  transpose_b16<<<dim3(512 / 32, S / 32), tb, 0, stream>>>(up2 + 512, vt, S, 1024, S);

  // attention chain, grouped per KV group for L2/L3 locality
  for (int g = 0; g < NKV; g++) {
    gemm_scores<<<dim3(16, 16, 4), 256, 0, stream>>>(qpack, kpack, attn, g);
    softmax_rows<<<dim3(S / 4, 4), 256, 0, stream>>>(attn, g * 4);
    gemm_pv<<<dim3(1, 16, 4), 256, 0, stream>>>(attn, vt, ctxb, g);
  }
  gemm_nt<float><<<dim3(16, 16), 256, 0, stream>>>(ctxb, wt_o, out0, Hdim, Hdim, Hdim, Hdim, Hdim, 1.f);
}

// Round 4
// 454.369 us; speedup vs baseline: 1.5148x; 1.5148x over previous
//
#include <hip/hip_runtime.h>
#include <stdint.h>

typedef __bf16 bf16;
typedef __bf16 bf16x8 __attribute__((ext_vector_type(8)));
typedef __bf16 bf16x4 __attribute__((ext_vector_type(4)));
typedef float f32x4 __attribute__((ext_vector_type(4)));

#define DEVFN static __device__ __forceinline__

constexpr int S = 2048, Hdim = 2048, NH = 16, NKV = 4, HD = 128, RHD = 64, QC = 1536, KVC = 512;
constexpr int QKD = HD + RHD;                 // 192
constexpr int DN = 2112;                      // merged down-proj width: QC + KVC + RHD
constexpr float RMS_EPS = 1e-6f;
constexpr float ATT_SCALE = 0.07216878364870323f;  // 1/sqrt(192)

// ---------------- reductions ----------------
DEVFN float wave_sum(float v) {
#pragma unroll
  for (int o = 32; o > 0; o >>= 1) v += __shfl_xor(v, o, 64);
  return v;
}
DEVFN float wave_max(float v) {
#pragma unroll
  for (int o = 32; o > 0; o >>= 1) v = fmaxf(v, __shfl_xor(v, o, 64));
  return v;
}
DEVFN float block_sum(float v) {
  __shared__ float red_s[4];
  v = wave_sum(v);
  int lane = threadIdx.x & 63, wid = threadIdx.x >> 6;
  if (lane == 0) red_s[wid] = v;
  __syncthreads();
  v = red_s[0] + red_s[1] + red_s[2] + red_s[3];
  __syncthreads();
  return v;
}
DEVFN float block_max(float v) {
  __shared__ float red_m[4];
  v = wave_max(v);
  int lane = threadIdx.x & 63, wid = threadIdx.x >> 6;
  if (lane == 0) red_m[wid] = v;
  __syncthreads();
  v = fmaxf(fmaxf(red_m[0], red_m[1]), fmaxf(red_m[2], red_m[3]));
  __syncthreads();
  return v;
}

// ---------------- async global->LDS (16B per lane) ----------------
DEVFN void gload16(const bf16* g, bf16* l) {
  __builtin_amdgcn_global_load_lds(
      (const __attribute__((address_space(1))) uint32_t*)g,
      (__attribute__((address_space(3))) uint32_t*)l, 16, 0, 0);
}

// ---------------- async GEMM core (m97 structure): C = A[M,K] * Bt[N,K]^T ---
template <typename OT>
DEVFN void gemm_core_async(const bf16* __restrict__ A, const bf16* __restrict__ Bt,
                           OT* __restrict__ C, int N, int lda, int ldb, int ldc,
                           int m0, int n0, float scale, int kend) {
  __shared__ alignas(16) bf16 As[128 * 32];
  __shared__ alignas(16) bf16 Bs[128 * 32];
  const int t = threadIdx.x;
  const int lane = t & 63;
  const int wm = ((t >> 7) & 1) * 64;
  const int wn = ((t >> 6) & 1) * 64;
  const int lr = lane & 15;
  const int lk = (lane >> 4) * 8;
  const int srow = t >> 2;
  const int scol = (t & 3) * 8;
  const bf16* Ab = A + (size_t)(m0 + srow) * lda + scol;
  const bf16* Bb = Bt + (size_t)(n0 + srow) * ldb + scol;
  bf16* Al = As + t * 8;
  bf16* Bl = Bs + t * 8;

  f32x4 acc[4][4];
#pragma unroll
  for (int i = 0; i < 4; i++)
#pragma unroll
    for (int j = 0; j < 4; j++) { f32x4 z = {0.f, 0.f, 0.f, 0.f}; acc[i][j] = z; }

  for (int kk = 0; kk < kend; kk += 32) {
    gload16(Ab + kk, Al);
    gload16(Ab + (size_t)64 * lda + kk, Al + 2048);
    gload16(Bb + kk, Bl);
    gload16(Bb + (size_t)64 * ldb + kk, Bl + 2048);
    __syncthreads();
    bf16x8 a[4], b[4];
#pragma unroll
    for (int i = 0; i < 4; i++)
      a[i] = *reinterpret_cast<const bf16x8*>(&As[(wm + i * 16 + lr) * 32 + lk]);
#pragma unroll
    for (int i = 0; i < 4; i++)
      b[i] = *reinterpret_cast<const bf16x8*>(&Bs[(wn + i * 16 + lr) * 32 + lk]);
#pragma unroll
    for (int i = 0; i < 4; i++)
#pragma unroll
      for (int j = 0; j < 4; j++)
        acc[i][j] = __builtin_amdgcn_mfma_f32_16x16x32_bf16(a[i], b[j], acc[i][j], 0, 0, 0);
    __syncthreads();
  }
  const int orow = (lane >> 4) * 4;
#pragma unroll
  for (int i = 0; i < 4; i++) {
#pragma unroll
    for (int j = 0; j < 4; j++) {
      int col = n0 + wn + j * 16 + lr;
      if (col < N) {
#pragma unroll
        for (int q = 0; q < 4; q++) {
          int row = m0 + wm + i * 16 + orow + q;
          C[(size_t)row * ldc + col] = (OT)(acc[i][j][q] * scale);
        }
      }
    }
  }
}

template <typename OT>
__global__ __launch_bounds__(256) void gemm_nt(const bf16* __restrict__ A, const bf16* __restrict__ Bt,
                                               OT* __restrict__ C, int N, int K, int lda,
                                               int ldb, int ldc, float scale) {
  gemm_core_async<OT>(A, Bt, C, N, lda, ldb, ldc, blockIdx.y * 128, blockIdx.x * 128, scale, K);
}

// scores for one KV group (4 heads), causal block-skip
__global__ __launch_bounds__(256) void gemm_scores(const bf16* __restrict__ qpack,
                                                   const bf16* __restrict__ kpack,
                                                   float* __restrict__ attn, int g) {
  int h = g * 4 + blockIdx.z;
  int m0 = blockIdx.y * 128, n0 = blockIdx.x * 128;
  if (n0 > m0) return;
  gemm_core_async<float>(qpack + (size_t)h * S * QKD, kpack + (size_t)g * S * QKD,
                         attn + (size_t)h * S * S, S, QKD, QKD, S, m0, n0, ATT_SCALE, QKD);
}

// ---------------- reg-staged PV (fp32 A) ----------------
DEVFN void stage8f(bf16* __restrict__ lds, const float* __restrict__ G, int grow, int gcol,
                   int ld, int lrow, int lcol) {
  const float* p = G + (size_t)grow * ld + gcol;
  float4 f0 = *reinterpret_cast<const float4*>(p);
  float4 f1 = *reinterpret_cast<const float4*>(p + 4);
  bf16x8 v;
  v[0] = (bf16)f0.x; v[1] = (bf16)f0.y; v[2] = (bf16)f0.z; v[3] = (bf16)f0.w;
  v[4] = (bf16)f1.x; v[5] = (bf16)f1.y; v[6] = (bf16)f1.z; v[7] = (bf16)f1.w;
  *reinterpret_cast<bf16x8*>(&lds[lrow * 40 + lcol]) = v;
}
DEVFN void stage8b(bf16* __restrict__ lds, const bf16* __restrict__ G, int grow, int gcol,
                   int ld, int lrow, int lcol) {
  *reinterpret_cast<bf16x8*>(&lds[lrow * 40 + lcol]) =
      *reinterpret_cast<const bf16x8*>(G + (size_t)grow * ld + gcol);
}

// PV over all heads: ctx[m, d] = sum_k attn[m,k] * vt[d,k], causal (k < m0+128)
__global__ __launch_bounds__(256) void gemm_pv(const float* __restrict__ attn,
                                               const bf16* __restrict__ vt,
                                               bf16* __restrict__ ctxb) {
  int h = blockIdx.z;
  const float* A = attn + (size_t)h * S * S;
  const bf16* Bt = vt + (size_t)(h >> 2) * HD * S;
  bf16* C = ctxb + h * HD;
  const int m0 = blockIdx.y * 128;
  const int kend = m0 + 128;  // causal
  __shared__ alignas(16) bf16 As[128 * 40];
  __shared__ alignas(16) bf16 Bs[128 * 40];
  const int t = threadIdx.x;
  const int lane = t & 63;
  const int wm = ((t >> 7) & 1) * 64;
  const int wn = ((t >> 6) & 1) * 64;
  const int lr = lane & 15;
  const int lk = (lane >> 4) * 8;
  const int r0 = t >> 2;
  const int c0 = (t & 3) * 8;
  f32x4 acc[4][4];
#pragma unroll
  for (int i = 0; i < 4; i++)
#pragma unroll
    for (int j = 0; j < 4; j++) { f32x4 z = {0.f, 0.f, 0.f, 0.f}; acc[i][j] = z; }

  for (int kk = 0; kk < kend; kk += 32) {
    stage8f(As, A, m0 + r0, kk + c0, S, r0, c0);
    stage8f(As, A, m0 + r0 + 64, kk + c0, S, r0 + 64, c0);
    stage8b(Bs, Bt, r0, kk + c0, S, r0, c0);
    stage8b(Bs, Bt, r0 + 64, kk + c0, S, r0 + 64, c0);
    __syncthreads();
    bf16x8 a[4], b[4];
#pragma unroll
    for (int i = 0; i < 4; i++)
      a[i] = *reinterpret_cast<const bf16x8*>(&As[(wm + i * 16 + lr) * 40 + lk]);
#pragma unroll
    for (int i = 0; i < 4; i++)
      b[i] = *reinterpret_cast<const bf16x8*>(&Bs[(wn + i * 16 + lr) * 40 + lk]);
#pragma unroll
    for (int i = 0; i < 4; i++)
#pragma unroll
      for (int j = 0; j < 4; j++)
        acc[i][j] = __builtin_amdgcn_mfma_f32_16x16x32_bf16(a[i], b[j], acc[i][j], 0, 0, 0);
    __syncthreads();
  }
  const int orow = (lane >> 4) * 4;
#pragma unroll
  for (int i = 0; i < 4; i++) {
#pragma unroll
    for (int j = 0; j < 4; j++) {
      int col = wn + j * 16 + lr;
#pragma unroll
      for (int q = 0; q < 4; q++) {
        int row = m0 + wm + i * 16 + orow + q;
        C[(size_t)row * Hdim + col] = (bf16)acc[i][j][q];
      }
    }
  }
}

// ---------------- elementwise / reshape ----------------
__global__ __launch_bounds__(256) void cast_f32_bf16(const float* __restrict__ in,
                                                     bf16* __restrict__ out, int n8) {
  int i = blockIdx.x * 256 + threadIdx.x;
  if (i >= n8) return;
  float4 f0 = *reinterpret_cast<const float4*>(in + (size_t)i * 8);
  float4 f1 = *reinterpret_cast<const float4*>(in + (size_t)i * 8 + 4);
  bf16x8 v;
  v[0] = (bf16)f0.x; v[1] = (bf16)f0.y; v[2] = (bf16)f0.z; v[3] = (bf16)f0.w;
  v[4] = (bf16)f1.x; v[5] = (bf16)f1.y; v[6] = (bf16)f1.z; v[7] = (bf16)f1.w;
  *reinterpret_cast<bf16x8*>(out + (size_t)i * 8) = v;
}

// batched fp32 [R][C] -> bf16 [C][R] transposes (8 jobs, one dispatch)
struct TJobs {
  const float* src[8];
  bf16* dst[8];
  int R[8], C[8], tiles[8];
};

__global__ __launch_bounds__(256) void transpose_batch(TJobs J) {
  int tile = blockIdx.x;
  int j = 0;
  while (tile >= J.tiles[j]) { tile -= J.tiles[j]; ++j; }
  const int C = J.C[j], R = J.R[j];
  int tcn = C >> 5;
  int rb = (tile / tcn) * 32, cb = (tile % tcn) * 32;
  const float* in = J.src[j];
  bf16* out = J.dst[j];
  __shared__ float tl[32][33];
  int tx = threadIdx.x, ty = threadIdx.y;
#pragma unroll
  for (int q = 0; q < 32; q += 8)
    tl[ty + q][tx] = in[(size_t)(rb + ty + q) * C + cb + tx];
  __syncthreads();
#pragma unroll
  for (int q = 0; q < 32; q += 8)
    out[(size_t)(cb + ty + q) * R + rb + tx] = (bf16)tl[tx][ty + q];
}

// bf16 [R][C] (ld=ild) -> bf16 [C][R] (ld=old_)
__global__ __launch_bounds__(256) void transpose_b16(const bf16* __restrict__ in,
                                                     bf16* __restrict__ out, int R, int ild, int old_) {
  __shared__ float tl[32][33];
  int tx = threadIdx.x, ty = threadIdx.y;
  int cb = blockIdx.x * 32, rb = blockIdx.y * 32;
#pragma unroll
  for (int q = 0; q < 32; q += 8)
    tl[ty + q][tx] = (float)in[(size_t)(rb + ty + q) * ild + cb + tx];
  __syncthreads();
#pragma unroll
  for (int q = 0; q < 32; q += 8)
    out[(size_t)(cb + ty + q) * old_ + rb + tx] = (bf16)tl[tx][ty + q];
}

// fused RMSNorm for cq (y==0) and ckv (y==1) reading merged dproj
__global__ __launch_bounds__(256) void rmsnorm_fused(const float* __restrict__ dproj,
                                                     const float* __restrict__ qw,
                                                     const float* __restrict__ kw,
                                                     bf16* __restrict__ cqb,
                                                     bf16* __restrict__ ckvb) {
  int row = blockIdx.x;
  bool isq = (blockIdx.y == 0);
  int C = isq ? QC : KVC;
  const float* p = dproj + (size_t)row * DN + (isq ? 0 : QC);
  const float* w = isq ? qw : kw;
  bf16* out = (isq ? cqb : ckvb) + (size_t)row * C;
  float ss = 0.f;
  for (int i = threadIdx.x * 4; i < C; i += 1024) {
    float4 v = *reinterpret_cast<const float4*>(p + i);
    ss += v.x * v.x + v.y * v.y + v.z * v.z + v.w * v.w;
  }
  ss = block_sum(ss);
  float r = rsqrtf(ss / (float)C + RMS_EPS);
  for (int i = threadIdx.x * 4; i < C; i += 1024) {
    float4 v = *reinterpret_cast<const float4*>(p + i);
    float4 g = *reinterpret_cast<const float4*>(w + i);
    bf16x4 o;
    o[0] = (bf16)(v.x * r * g.x); o[1] = (bf16)(v.y * r * g.y);
    o[2] = (bf16)(v.z * r * g.z); o[3] = (bf16)(v.w * r * g.w);
    *reinterpret_cast<bf16x4*>(out + i) = o;
  }
}

// fused: pack qc slice of up1 into qpack + RoPE'd qr into qpack[...,128:]
__global__ __launch_bounds__(256) void build_qpack(const bf16* __restrict__ up1,
                                                   const float* __restrict__ cosp,
                                                   const float* __restrict__ sinp,
                                                   bf16* __restrict__ qpack) {
  int idx = blockIdx.x * 256 + threadIdx.x;
  const int P = NH * S * 16;  // 8-elem chunks of qc
  if (idx < P) {
    int d8 = idx & 15, s = (idx >> 4) & (S - 1), h = idx >> 15;
    int4 v = *reinterpret_cast<const int4*>(up1 + (size_t)s * 3072 + h * HD + d8 * 8);
    *reinterpret_cast<int4*>(qpack + ((size_t)h * S + s) * QKD + d8 * 8) = v;
  } else {
    int j = idx - P;
    int d0 = (j & 7) * 8, s = (j >> 3) & (S - 1), h = j >> 14;
    const bf16* xr = up1 + (size_t)s * 3072 + 2048 + h * RHD;
    bf16x8 xa = *reinterpret_cast<const bf16x8*>(xr + d0);
    bf16x8 xb = *reinterpret_cast<const bf16x8*>(xr + (d0 ^ 32));
    float sign = (d0 < 32) ? -1.f : 1.f;
    const float* cr = cosp + s * RHD + d0;
    const float* sr = sinp + s * RHD + d0;
    bf16x8 o;
#pragma unroll
    for (int i = 0; i < 8; i++)
      o[i] = (bf16)((float)xa[i] * cr[i] + sign * (float)xb[i] * sr[i]);
    *reinterpret_cast<bf16x8*>(qpack + ((size_t)h * S + s) * QKD + HD + d0) = o;
  }
}

// fused: pack kc slice of up2 into kpack + RoPE'd kr (from dproj col 2048) into all groups
__global__ __launch_bounds__(256) void build_kpack(const bf16* __restrict__ up2,
                                                   const float* __restrict__ dproj,
                                                   const float* __restrict__ cosp,
                                                   const float* __restrict__ sinp,
                                                   bf16* __restrict__ kpack) {
  int idx = blockIdx.x * 256 + threadIdx.x;
  const int P = NKV * S * 16;
  if (idx < P) {
    int d8 = idx & 15, s = (idx >> 4) & (S - 1), g = idx >> 15;
    int4 v = *reinterpret_cast<const int4*>(up2 + (size_t)s * 1024 + g * HD + d8 * 8);
    *reinterpret_cast<int4*>(kpack + ((size_t)g * S + s) * QKD + d8 * 8) = v;
  } else {
    int j = idx - P;
    int d0 = (j & 7) * 8, s = j >> 3;
    const float* xr = dproj + (size_t)s * DN + 2048;
    float4 a0 = *reinterpret_cast<const float4*>(xr + d0);
    float4 a1 = *reinterpret_cast<const float4*>(xr + d0 + 4);
    float4 b0 = *reinterpret_cast<const float4*>(xr + (d0 ^ 32));
    float4 b1 = *reinterpret_cast<const float4*>(xr + (d0 ^ 32) + 4);
    float sign = (d0 < 32) ? -1.f : 1.f;
    const float* cr = cosp + s * RHD + d0;
    const float* sr = sinp + s * RHD + d0;
    float xa[8] = {a0.x, a0.y, a0.z, a0.w, a1.x, a1.y, a1.z, a1.w};
    float xb[8] = {b0.x, b0.y, b0.z, b0.w, b1.x, b1.y, b1.z, b1.w};
    bf16x8 o;
#pragma unroll
    for (int i = 0; i < 8; i++)
      o[i] = (bf16)(xa[i] * cr[i] + sign * xb[i] * sr[i]);
#pragma unroll
    for (int g = 0; g < NKV; g++)
      *reinterpret_cast<bf16x8*>(kpack + ((size_t)g * S + s) * QKD + HD + d0) = o;
  }
}

// block-per-row causal softmax; 256 threads x 8 elems = full 2048 row in regs.
// Compile-time-indexed registers only (no scratch); writes full row incl. zero tail.
__global__ __launch_bounds__(256) void softmax_rows(float* __restrict__ attn, int h0) {
  int s = blockIdx.x, h = h0 + blockIdx.y;
  float* row = attn + ((size_t)h * S + s) * S;
  const int n = s + 1;
  const int t4 = threadIdx.x * 4;
  float4 v0 = *reinterpret_cast<const float4*>(row + t4);
  float4 v1 = *reinterpret_cast<const float4*>(row + 1024 + t4);
  float e0[4] = {v0.x, v0.y, v0.z, v0.w};
  float e1[4] = {v1.x, v1.y, v1.z, v1.w};
  float m = -1e30f;
#pragma unroll
  for (int k = 0; k < 4; k++) {
    e0[k] = (t4 + k < n) ? e0[k] : -1e30f;
    e1[k] = (1024 + t4 + k < n) ? e1[k] : -1e30f;
    m = fmaxf(m, fmaxf(e0[k], e1[k]));
  }
  m = block_max(m);
  float l = 0.f;
#pragma unroll
  for (int k = 0; k < 4; k++) {
    e0[k] = (t4 + k < n) ? __expf(e0[k] - m) : 0.f;
    e1[k] = (1024 + t4 + k < n) ? __expf(e1[k] - m) : 0.f;
    l += e0[k] + e1[k];
  }
  l = block_sum(l);
  float inv = 1.0f / l;
  float4 o0 = make_float4(e0[0] * inv, e0[1] * inv, e0[2] * inv, e0[3] * inv);
  float4 o1 = make_float4(e1[0] * inv, e1[1] * inv, e1[2] * inv, e1[3] * inv);
  *reinterpret_cast<float4*>(row + t4) = o0;
  *reinterpret_cast<float4*>(row + 1024 + t4) = o1;
}

// ---------------- launcher ----------------
extern "C" void kernel_launch(void* const* d_in, const int* in_sizes, int n_in, void* d_out,
                              int out_size, void* d_ws, size_t ws_size, hipStream_t stream) {
  const float* Xf = (const float*)d_in[0];
  const float* cosp = (const float*)d_in[1];
  const float* sinp = (const float*)d_in[2];
  const float* w_down_q = (const float*)d_in[4];
  const float* w_up_q = (const float*)d_in[5];
  const float* w_qr = (const float*)d_in[6];
  const float* w_down_kv = (const float*)d_in[7];
  const float* w_up_k = (const float*)d_in[8];
  const float* w_up_v = (const float*)d_in[9];
  const float* w_kr = (const float*)d_in[10];
  const float* w_o = (const float*)d_in[11];
  const float* q_norm_w = (const float*)d_in[12];
  const float* k_norm_w = (const float*)d_in[13];

  float* out0 = (float*)d_out;
  float* attn = out0 + (size_t)S * Hdim;

  char* base = (char*)d_ws;
  size_t off = 0;
  auto carve = [&](size_t bytes) -> void* {
    void* p = base + off;
    off += (bytes + 255) & ~(size_t)255;
    return p;
  };
  bf16* Xb      = (bf16*)carve((size_t)S * Hdim * 2);
  bf16* wt_down = (bf16*)carve((size_t)2176 * 2048 * 2);  // [2112(+pad)][2048]
  bf16* wt_up1  = (bf16*)carve((size_t)3072 * QC * 2);    // [3072][1536]
  bf16* wt_up2  = (bf16*)carve((size_t)1024 * KVC * 2);   // [1024][512]
  bf16* wt_o    = (bf16*)carve((size_t)Hdim * Hdim * 2);
  float* dproj  = (float*)carve((size_t)S * DN * 4);      // [2048][2112]
  bf16* cqb     = (bf16*)carve((size_t)S * QC * 2);
  bf16* ckvb    = (bf16*)carve((size_t)S * KVC * 2);
  bf16* up1     = (bf16*)carve((size_t)S * 3072 * 2);     // [s][qc 0:2048 | qr 2048:3072]
  bf16* up2     = (bf16*)carve((size_t)S * 1024 * 2);     // [s][kc 0:512 | v 512:1024]
  bf16* qpack   = (bf16*)carve((size_t)NH * S * QKD * 2);
  bf16* kpack   = (bf16*)carve((size_t)NKV * S * QKD * 2);
  bf16* vt      = (bf16*)carve((size_t)NKV * HD * S * 2);
  bf16* ctxb    = (bf16*)carve((size_t)S * Hdim * 2);
  (void)in_sizes; (void)n_in; (void)out_size; (void)ws_size;

  dim3 tb(32, 8);
  cast_f32_bf16<<<S * Hdim / 8 / 256, 256, 0, stream>>>(Xf, Xb, S * Hdim / 8);

  TJobs J;
  const float* srcs[8] = {w_down_q, w_down_kv, w_kr, w_up_q, w_qr, w_up_k, w_up_v, w_o};
  bf16* dsts[8] = {wt_down, wt_down + (size_t)QC * 2048, wt_down + (size_t)2048 * 2048,
                   wt_up1, wt_up1 + (size_t)2048 * QC, wt_up2, wt_up2 + (size_t)512 * KVC, wt_o};
  int Rs[8] = {2048, 2048, 2048, 1536, 1536, 512, 512, 2048};
  int Cs[8] = {1536, 512, 64, 2048, 1024, 512, 512, 2048};
  int total_tiles = 0;
  for (int j = 0; j < 8; j++) {
    J.src[j] = srcs[j]; J.dst[j] = dsts[j]; J.R[j] = Rs[j]; J.C[j] = Cs[j];
    J.tiles[j] = (Rs[j] / 32) * (Cs[j] / 32);
    total_tiles += J.tiles[j];
  }
  transpose_batch<<<total_tiles, tb, 0, stream>>>(J);

  // merged down projection: [S][2112] = Xb @ [wdq | wdkv | wkr]
  gemm_nt<float><<<dim3(17, 16), 256, 0, stream>>>(Xb, wt_down, dproj, DN, Hdim, Hdim, Hdim, DN, 1.f);
  rmsnorm_fused<<<dim3(S, 2), 256, 0, stream>>>(dproj, q_norm_w, k_norm_w, cqb, ckvb);

  // merged up projections
  gemm_nt<bf16><<<dim3(24, 16), 256, 0, stream>>>(cqb, wt_up1, up1, 3072, QC, QC, QC, 3072, 1.f);
  gemm_nt<bf16><<<dim3(8, 16), 256, 0, stream>>>(ckvb, wt_up2, up2, 1024, KVC, KVC, KVC, 1024, 1.f);

  build_qpack<<<(NH * S * 16 + NH * S * 8) / 256, 256, 0, stream>>>(up1, cosp, sinp, qpack);
  build_kpack<<<(NKV * S * 16 + S * 8) / 256, 256, 0, stream>>>(up2, dproj, cosp, sinp, kpack);
  transpose_b16<<<dim3(512 / 32, S / 32), tb, 0, stream>>>(up2 + 512, vt, S, 1024, S);

  // scores -> softmax per KV group (L3 locality), then PV over all heads
  for (int g = 0; g < NKV; g++) {
    gemm_scores<<<dim3(16, 16, 4), 256, 0, stream>>>(qpack, kpack, attn, g);
    softmax_rows<<<dim3(S, 4), 256, 0, stream>>>(attn, g * 4);
  }
  gemm_pv<<<dim3(1, 16, 16), 256, 0, stream>>>(attn, vt, ctxb);
  gemm_nt<float><<<dim3(16, 16), 256, 0, stream>>>(ctxb, wt_o, out0, Hdim, Hdim, Hdim, Hdim, Hdim, 1.f);
}

// Round 5
// 431.932 us; speedup vs baseline: 1.5935x; 1.0519x over previous
//
#include <hip/hip_runtime.h>
#include <stdint.h>

typedef __bf16 bf16;
typedef __bf16 bf16x8 __attribute__((ext_vector_type(8)));
typedef __bf16 bf16x4 __attribute__((ext_vector_type(4)));
typedef float f32x4 __attribute__((ext_vector_type(4)));

#define DEVFN static __device__ __forceinline__

constexpr int S = 2048, Hdim = 2048, NH = 16, NKV = 4, HD = 128, RHD = 64, QC = 1536, KVC = 512;
constexpr int QKD = HD + RHD;                 // 192
constexpr int DN = 2112;                      // merged down-proj width: QC + KVC + RHD
constexpr float RMS_EPS = 1e-6f;
constexpr float ATT_SCALE = 0.07216878364870323f;  // 1/sqrt(192)

// ---------------- reductions ----------------
DEVFN float wave_sum(float v) {
#pragma unroll
  for (int o = 32; o > 0; o >>= 1) v += __shfl_xor(v, o, 64);
  return v;
}
DEVFN float block_sum(float v) {
  __shared__ float red_s[4];
  v = wave_sum(v);
  int lane = threadIdx.x & 63, wid = threadIdx.x >> 6;
  if (lane == 0) red_s[wid] = v;
  __syncthreads();
  v = red_s[0] + red_s[1] + red_s[2] + red_s[3];
  __syncthreads();
  return v;
}

// ---------------- async global->LDS (16B per lane) ----------------
DEVFN void gload16(const bf16* g, bf16* l) {
  __builtin_amdgcn_global_load_lds(
      (const __attribute__((address_space(1))) uint32_t*)g,
      (__attribute__((address_space(3))) uint32_t*)l, 16, 0, 0);
}

// ---------------- async GEMM core (m97 structure): C = A[M,K] * Bt[N,K]^T ---
template <typename OT>
DEVFN void gemm_core_async(const bf16* __restrict__ A, const bf16* __restrict__ Bt,
                           OT* __restrict__ C, int N, int lda, int ldb, int ldc,
                           int m0, int n0, float scale, int kend) {
  __shared__ alignas(16) bf16 As[128 * 32];
  __shared__ alignas(16) bf16 Bs[128 * 32];
  const int t = threadIdx.x;
  const int lane = t & 63;
  const int wm = ((t >> 7) & 1) * 64;
  const int wn = ((t >> 6) & 1) * 64;
  const int lr = lane & 15;
  const int lk = (lane >> 4) * 8;
  const int srow = t >> 2;
  const int scol = (t & 3) * 8;
  const bf16* Ab = A + (size_t)(m0 + srow) * lda + scol;
  const bf16* Bb = Bt + (size_t)(n0 + srow) * ldb + scol;
  bf16* Al = As + t * 8;
  bf16* Bl = Bs + t * 8;

  f32x4 acc[4][4];
#pragma unroll
  for (int i = 0; i < 4; i++)
#pragma unroll
    for (int j = 0; j < 4; j++) { f32x4 z = {0.f, 0.f, 0.f, 0.f}; acc[i][j] = z; }

  for (int kk = 0; kk < kend; kk += 32) {
    gload16(Ab + kk, Al);
    gload16(Ab + (size_t)64 * lda + kk, Al + 2048);
    gload16(Bb + kk, Bl);
    gload16(Bb + (size_t)64 * ldb + kk, Bl + 2048);
    __syncthreads();
    bf16x8 a[4], b[4];
#pragma unroll
    for (int i = 0; i < 4; i++)
      a[i] = *reinterpret_cast<const bf16x8*>(&As[(wm + i * 16 + lr) * 32 + lk]);
#pragma unroll
    for (int i = 0; i < 4; i++)
      b[i] = *reinterpret_cast<const bf16x8*>(&Bs[(wn + i * 16 + lr) * 32 + lk]);
#pragma unroll
    for (int i = 0; i < 4; i++)
#pragma unroll
      for (int j = 0; j < 4; j++)
        acc[i][j] = __builtin_amdgcn_mfma_f32_16x16x32_bf16(a[i], b[j], acc[i][j], 0, 0, 0);
    __syncthreads();
  }
  const int orow = (lane >> 4) * 4;
#pragma unroll
  for (int i = 0; i < 4; i++) {
#pragma unroll
    for (int j = 0; j < 4; j++) {
      int col = n0 + wn + j * 16 + lr;
      if (col < N) {
#pragma unroll
        for (int q = 0; q < 4; q++) {
          int row = m0 + wm + i * 16 + orow + q;
          C[(size_t)row * ldc + col] = (OT)(acc[i][j][q] * scale);
        }
      }
    }
  }
}

template <typename OT>
__global__ __launch_bounds__(256) void gemm_nt(const bf16* __restrict__ A, const bf16* __restrict__ Bt,
                                               OT* __restrict__ C, int N, int K, int lda,
                                               int ldb, int ldc, float scale) {
  gemm_core_async<OT>(A, Bt, C, N, lda, ldb, ldc, blockIdx.y * 128, blockIdx.x * 128, scale, K);
}

// raw causal scores, all heads in one launch; writes only n0<=m0 blocks
__global__ __launch_bounds__(256) void gemm_scores(const bf16* __restrict__ qpack,
                                                   const bf16* __restrict__ kpack,
                                                   float* __restrict__ attn) {
  int h = blockIdx.z;
  int g = h >> 2;
  int m0 = blockIdx.y * 128, n0 = blockIdx.x * 128;
  if (n0 > m0) return;
  gemm_core_async<float>(qpack + (size_t)h * S * QKD, kpack + (size_t)g * S * QKD,
                         attn + (size_t)h * S * S, S, QKD, QKD, S, m0, n0, ATT_SCALE, QKD);
}

// ---------------- LDS staging helper (bf16 source) ----------------
DEVFN void stage8b(bf16* __restrict__ lds, const bf16* __restrict__ G, int grow, int gcol,
                   int ld, int lrow, int lcol) {
  *reinterpret_cast<bf16x8*>(&lds[lrow * 40 + lcol]) =
      *reinterpret_cast<const bf16x8*>(G + (size_t)grow * ld + gcol);
}

// ---------------- fused softmax + PV + normalized-attn write ----------------
// One block = 64-row strip of one head. Phase 1: row stats over raw scores.
// Phase 2: k-loop: normalize (write attn fp32) + bf16 P into LDS + PV MFMA.
// Tail: zero-fill attn[kend..S). 4 waves: 2x2 of 32x64 (acc 2x4 frags).
__global__ __launch_bounds__(256) void smpv(float* __restrict__ attn,
                                            const bf16* __restrict__ vt,
                                            bf16* __restrict__ ctxb) {
  const int strip = blockIdx.x;   // 0..31
  const int h = blockIdx.y;       // 0..15
  const int m0 = strip * 64;
  const int kend = m0 + 64;       // causal: rows [m0, m0+64) need k <= m0+63
  float* A = attn + (size_t)h * S * S;
  const bf16* Bt = vt + (size_t)(h >> 2) * HD * S;
  bf16* C = ctxb + h * HD;

  __shared__ alignas(16) bf16 As[64 * 40];
  __shared__ alignas(16) bf16 Bs[128 * 40];
  __shared__ float statm[64], statl[64];

  const int t = threadIdx.x;
  const int lane = t & 63;
  const int r0 = t >> 2;          // row within strip, 0..63
  const int part = t & 3;
  const int c0 = part * 8;
  const int rowg = m0 + r0;
  float* Arow = A + (size_t)rowg * S;

  // ---- phase 1a: masked row max ----
  float m = -1e30f;
  for (int c = part * 16; c < kend; c += 64) {
#pragma unroll
    for (int u = 0; u < 4; u++) {
      float4 v = *reinterpret_cast<const float4*>(Arow + c + u * 4);
      int k = c + u * 4;
      m = fmaxf(m, (k     <= rowg) ? v.x : -1e30f);
      m = fmaxf(m, (k + 1 <= rowg) ? v.y : -1e30f);
      m = fmaxf(m, (k + 2 <= rowg) ? v.z : -1e30f);
      m = fmaxf(m, (k + 3 <= rowg) ? v.w : -1e30f);
    }
  }
  m = fmaxf(m, __shfl_xor(m, 1, 64));
  m = fmaxf(m, __shfl_xor(m, 2, 64));
  // ---- phase 1b: masked sum of exp ----
  float l = 0.f;
  for (int c = part * 16; c < kend; c += 64) {
#pragma unroll
    for (int u = 0; u < 4; u++) {
      float4 v = *reinterpret_cast<const float4*>(Arow + c + u * 4);
      int k = c + u * 4;
      l += (k     <= rowg) ? __expf(v.x - m) : 0.f;
      l += (k + 1 <= rowg) ? __expf(v.y - m) : 0.f;
      l += (k + 2 <= rowg) ? __expf(v.z - m) : 0.f;
      l += (k + 3 <= rowg) ? __expf(v.w - m) : 0.f;
    }
  }
  l += __shfl_xor(l, 1, 64);
  l += __shfl_xor(l, 2, 64);
  if (part == 0) { statm[r0] = m; statl[r0] = 1.0f / l; }
  __syncthreads();

  const int wm = (t >> 7) * 32;          // wave row: 0 or 32
  const int wn = ((t >> 6) & 1) * 64;    // wave col: 0 or 64
  const int lr = lane & 15;
  const int lk = (lane >> 4) * 8;
  const float mr = statm[r0];
  const float invl = statl[r0];

  f32x4 acc[2][4];
#pragma unroll
  for (int i = 0; i < 2; i++)
#pragma unroll
    for (int j = 0; j < 4; j++) { f32x4 z = {0.f, 0.f, 0.f, 0.f}; acc[i][j] = z; }

  for (int kk = 0; kk < kend; kk += 32) {
    // stage A: read raw, normalize, write back fp32, stash bf16 in LDS
    {
      float* p = Arow + kk + c0;
      float4 f0 = *reinterpret_cast<const float4*>(p);
      float4 f1 = *reinterpret_cast<const float4*>(p + 4);
      float pv[8] = {f0.x, f0.y, f0.z, f0.w, f1.x, f1.y, f1.z, f1.w};
      bf16x8 vb;
#pragma unroll
      for (int e = 0; e < 8; e++) {
        float pe = (kk + c0 + e <= rowg) ? __expf(pv[e] - mr) * invl : 0.f;
        pv[e] = pe;
        vb[e] = (bf16)pe;
      }
      *reinterpret_cast<float4*>(p) = make_float4(pv[0], pv[1], pv[2], pv[3]);
      *reinterpret_cast<float4*>(p + 4) = make_float4(pv[4], pv[5], pv[6], pv[7]);
      *reinterpret_cast<bf16x8*>(&As[r0 * 40 + c0]) = vb;
    }
    stage8b(Bs, Bt, r0, kk + c0, S, r0, c0);
    stage8b(Bs, Bt, r0 + 64, kk + c0, S, r0 + 64, c0);
    __syncthreads();
    bf16x8 a[2], b[4];
#pragma unroll
    for (int i = 0; i < 2; i++)
      a[i] = *reinterpret_cast<const bf16x8*>(&As[(wm + i * 16 + lr) * 40 + lk]);
#pragma unroll
    for (int j = 0; j < 4; j++)
      b[j] = *reinterpret_cast<const bf16x8*>(&Bs[(wn + j * 16 + lr) * 40 + lk]);
#pragma unroll
    for (int i = 0; i < 2; i++)
#pragma unroll
      for (int j = 0; j < 4; j++)
        acc[i][j] = __builtin_amdgcn_mfma_f32_16x16x32_bf16(a[i], b[j], acc[i][j], 0, 0, 0);
    __syncthreads();
  }

  // zero-fill causal tail [kend, S)
  const float4 zz = make_float4(0.f, 0.f, 0.f, 0.f);
  for (int kk = kend; kk < S; kk += 32) {
    float* p = Arow + kk + c0;
    *reinterpret_cast<float4*>(p) = zz;
    *reinterpret_cast<float4*>(p + 4) = zz;
  }

  // epilogue: ctx write
  const int orow = (lane >> 4) * 4;
#pragma unroll
  for (int i = 0; i < 2; i++) {
#pragma unroll
    for (int j = 0; j < 4; j++) {
      int col = wn + j * 16 + lr;
#pragma unroll
      for (int q = 0; q < 4; q++) {
        int row = m0 + wm + i * 16 + orow + q;
        C[(size_t)row * Hdim + col] = (bf16)acc[i][j][q];
      }
    }
  }
}

// ---------------- elementwise / reshape ----------------
__global__ __launch_bounds__(256) void cast_f32_bf16(const float* __restrict__ in,
                                                     bf16* __restrict__ out, int n8) {
  int i = blockIdx.x * 256 + threadIdx.x;
  if (i >= n8) return;
  float4 f0 = *reinterpret_cast<const float4*>(in + (size_t)i * 8);
  float4 f1 = *reinterpret_cast<const float4*>(in + (size_t)i * 8 + 4);
  bf16x8 v;
  v[0] = (bf16)f0.x; v[1] = (bf16)f0.y; v[2] = (bf16)f0.z; v[3] = (bf16)f0.w;
  v[4] = (bf16)f1.x; v[5] = (bf16)f1.y; v[6] = (bf16)f1.z; v[7] = (bf16)f1.w;
  *reinterpret_cast<bf16x8*>(out + (size_t)i * 8) = v;
}

// batched fp32 [R][C] -> bf16 [C][R] transposes (8 jobs, one dispatch)
struct TJobs {
  const float* src[8];
  bf16* dst[8];
  int R[8], C[8], tiles[8];
};

__global__ __launch_bounds__(256) void transpose_batch(TJobs J) {
  int tile = blockIdx.x;
  int j = 0;
  while (tile >= J.tiles[j]) { tile -= J.tiles[j]; ++j; }
  const int C = J.C[j], R = J.R[j];
  int tcn = C >> 5;
  int rb = (tile / tcn) * 32, cb = (tile % tcn) * 32;
  const float* in = J.src[j];
  bf16* out = J.dst[j];
  __shared__ float tl[32][33];
  int tx = threadIdx.x, ty = threadIdx.y;
#pragma unroll
  for (int q = 0; q < 32; q += 8)
    tl[ty + q][tx] = in[(size_t)(rb + ty + q) * C + cb + tx];
  __syncthreads();
#pragma unroll
  for (int q = 0; q < 32; q += 8)
    out[(size_t)(cb + ty + q) * R + rb + tx] = (bf16)tl[tx][ty + q];
}

// bf16 [R][C] (ld=ild) -> bf16 [C][R] (ld=old_)
__global__ __launch_bounds__(256) void transpose_b16(const bf16* __restrict__ in,
                                                     bf16* __restrict__ out, int R, int ild, int old_) {
  __shared__ float tl[32][33];
  int tx = threadIdx.x, ty = threadIdx.y;
  int cb = blockIdx.x * 32, rb = blockIdx.y * 32;
#pragma unroll
  for (int q = 0; q < 32; q += 8)
    tl[ty + q][tx] = (float)in[(size_t)(rb + ty + q) * ild + cb + tx];
  __syncthreads();
#pragma unroll
  for (int q = 0; q < 32; q += 8)
    out[(size_t)(cb + ty + q) * old_ + rb + tx] = (bf16)tl[tx][ty + q];
}

// fused RMSNorm for cq (y==0) and ckv (y==1) reading merged dproj
__global__ __launch_bounds__(256) void rmsnorm_fused(const float* __restrict__ dproj,
                                                     const float* __restrict__ qw,
                                                     const float* __restrict__ kw,
                                                     bf16* __restrict__ cqb,
                                                     bf16* __restrict__ ckvb) {
  int row = blockIdx.x;
  bool isq = (blockIdx.y == 0);
  int C = isq ? QC : KVC;
  const float* p = dproj + (size_t)row * DN + (isq ? 0 : QC);
  const float* w = isq ? qw : kw;
  bf16* out = (isq ? cqb : ckvb) + (size_t)row * C;
  float ss = 0.f;
  for (int i = threadIdx.x * 4; i < C; i += 1024) {
    float4 v = *reinterpret_cast<const float4*>(p + i);
    ss += v.x * v.x + v.y * v.y + v.z * v.z + v.w * v.w;
  }
  ss = block_sum(ss);
  float r = rsqrtf(ss / (float)C + RMS_EPS);
  for (int i = threadIdx.x * 4; i < C; i += 1024) {
    float4 v = *reinterpret_cast<const float4*>(p + i);
    float4 g = *reinterpret_cast<const float4*>(w + i);
    bf16x4 o;
    o[0] = (bf16)(v.x * r * g.x); o[1] = (bf16)(v.y * r * g.y);
    o[2] = (bf16)(v.z * r * g.z); o[3] = (bf16)(v.w * r * g.w);
    *reinterpret_cast<bf16x4*>(out + i) = o;
  }
}

// fused: pack qc slice of up1 into qpack + RoPE'd qr into qpack[...,128:]
__global__ __launch_bounds__(256) void build_qpack(const bf16* __restrict__ up1,
                                                   const float* __restrict__ cosp,
                                                   const float* __restrict__ sinp,
                                                   bf16* __restrict__ qpack) {
  int idx = blockIdx.x * 256 + threadIdx.x;
  const int P = NH * S * 16;  // 8-elem chunks of qc
  if (idx < P) {
    int d8 = idx & 15, s = (idx >> 4) & (S - 1), h = idx >> 15;
    int4 v = *reinterpret_cast<const int4*>(up1 + (size_t)s * 3072 + h * HD + d8 * 8);
    *reinterpret_cast<int4*>(qpack + ((size_t)h * S + s) * QKD + d8 * 8) = v;
  } else {
    int j = idx - P;
    int d0 = (j & 7) * 8, s = (j >> 3) & (S - 1), h = j >> 14;
    const bf16* xr = up1 + (size_t)s * 3072 + 2048 + h * RHD;
    bf16x8 xa = *reinterpret_cast<const bf16x8*>(xr + d0);
    bf16x8 xb = *reinterpret_cast<const bf16x8*>(xr + (d0 ^ 32));
    float sign = (d0 < 32) ? -1.f : 1.f;
    const float* cr = cosp + s * RHD + d0;
    const float* sr = sinp + s * RHD + d0;
    bf16x8 o;
#pragma unroll
    for (int i = 0; i < 8; i++)
      o[i] = (bf16)((float)xa[i] * cr[i] + sign * (float)xb[i] * sr[i]);
    *reinterpret_cast<bf16x8*>(qpack + ((size_t)h * S + s) * QKD + HD + d0) = o;
  }
}

// fused: pack kc slice of up2 into kpack + RoPE'd kr (from dproj col 2048) into all groups
__global__ __launch_bounds__(256) void build_kpack(const bf16* __restrict__ up2,
                                                   const float* __restrict__ dproj,
                                                   const float* __restrict__ cosp,
                                                   const float* __restrict__ sinp,
                                                   bf16* __restrict__ kpack) {
  int idx = blockIdx.x * 256 + threadIdx.x;
  const int P = NKV * S * 16;
  if (idx < P) {
    int d8 = idx & 15, s = (idx >> 4) & (S - 1), g = idx >> 15;
    int4 v = *reinterpret_cast<const int4*>(up2 + (size_t)s * 1024 + g * HD + d8 * 8);
    *reinterpret_cast<int4*>(kpack + ((size_t)g * S + s) * QKD + d8 * 8) = v;
  } else {
    int j = idx - P;
    int d0 = (j & 7) * 8, s = j >> 3;
    const float* xr = dproj + (size_t)s * DN + 2048;
    float4 a0 = *reinterpret_cast<const float4*>(xr + d0);
    float4 a1 = *reinterpret_cast<const float4*>(xr + d0 + 4);
    float4 b0 = *reinterpret_cast<const float4*>(xr + (d0 ^ 32));
    float4 b1 = *reinterpret_cast<const float4*>(xr + (d0 ^ 32) + 4);
    float sign = (d0 < 32) ? -1.f : 1.f;
    const float* cr = cosp + s * RHD + d0;
    const float* sr = sinp + s * RHD + d0;
    float xa[8] = {a0.x, a0.y, a0.z, a0.w, a1.x, a1.y, a1.z, a1.w};
    float xb[8] = {b0.x, b0.y, b0.z, b0.w, b1.x, b1.y, b1.z, b1.w};
    bf16x8 o;
#pragma unroll
    for (int i = 0; i < 8; i++)
      o[i] = (bf16)(xa[i] * cr[i] + sign * xb[i] * sr[i]);
#pragma unroll
    for (int g = 0; g < NKV; g++)
      *reinterpret_cast<bf16x8*>(kpack + ((size_t)g * S + s) * QKD + HD + d0) = o;
  }
}

// ---------------- launcher ----------------
extern "C" void kernel_launch(void* const* d_in, const int* in_sizes, int n_in, void* d_out,
                              int out_size, void* d_ws, size_t ws_size, hipStream_t stream) {
  const float* Xf = (const float*)d_in[0];
  const float* cosp = (const float*)d_in[1];
  const float* sinp = (const float*)d_in[2];
  const float* w_down_q = (const float*)d_in[4];
  const float* w_up_q = (const float*)d_in[5];
  const float* w_qr = (const float*)d_in[6];
  const float* w_down_kv = (const float*)d_in[7];
  const float* w_up_k = (const float*)d_in[8];
  const float* w_up_v = (const float*)d_in[9];
  const float* w_kr = (const float*)d_in[10];
  const float* w_o = (const float*)d_in[11];
  const float* q_norm_w = (const float*)d_in[12];
  const float* k_norm_w = (const float*)d_in[13];

  float* out0 = (float*)d_out;
  float* attn = out0 + (size_t)S * Hdim;

  char* base = (char*)d_ws;
  size_t off = 0;
  auto carve = [&](size_t bytes) -> void* {
    void* p = base + off;
    off += (bytes + 255) & ~(size_t)255;
    return p;
  };
  bf16* Xb      = (bf16*)carve((size_t)S * Hdim * 2);
  bf16* wt_down = (bf16*)carve((size_t)2176 * 2048 * 2);  // [2112(+pad)][2048]
  bf16* wt_up1  = (bf16*)carve((size_t)3072 * QC * 2);    // [3072][1536]
  bf16* wt_up2  = (bf16*)carve((size_t)1024 * KVC * 2);   // [1024][512]
  bf16* wt_o    = (bf16*)carve((size_t)Hdim * Hdim * 2);
  float* dproj  = (float*)carve((size_t)S * DN * 4);      // [2048][2112]
  bf16* cqb     = (bf16*)carve((size_t)S * QC * 2);
  bf16* ckvb    = (bf16*)carve((size_t)S * KVC * 2);
  bf16* up1     = (bf16*)carve((size_t)S * 3072 * 2);     // [s][qc 0:2048 | qr 2048:3072]
  bf16* up2     = (bf16*)carve((size_t)S * 1024 * 2);     // [s][kc 0:512 | v 512:1024]
  bf16* qpack   = (bf16*)carve((size_t)NH * S * QKD * 2);
  bf16* kpack   = (bf16*)carve((size_t)NKV * S * QKD * 2);
  bf16* vt      = (bf16*)carve((size_t)NKV * HD * S * 2);
  bf16* ctxb    = (bf16*)carve((size_t)S * Hdim * 2);
  (void)in_sizes; (void)n_in; (void)out_size; (void)ws_size;

  dim3 tb(32, 8);
  cast_f32_bf16<<<S * Hdim / 8 / 256, 256, 0, stream>>>(Xf, Xb, S * Hdim / 8);

  TJobs J;
  const float* srcs[8] = {w_down_q, w_down_kv, w_kr, w_up_q, w_qr, w_up_k, w_up_v, w_o};
  bf16* dsts[8] = {wt_down, wt_down + (size_t)QC * 2048, wt_down + (size_t)2048 * 2048,
                   wt_up1, wt_up1 + (size_t)2048 * QC, wt_up2, wt_up2 + (size_t)512 * KVC, wt_o};
  int Rs[8] = {2048, 2048, 2048, 1536, 1536, 512, 512, 2048};
  int Cs[8] = {1536, 512, 64, 2048, 1024, 512, 512, 2048};
  int total_tiles = 0;
  for (int j = 0; j < 8; j++) {
    J.src[j] = srcs[j]; J.dst[j] = dsts[j]; J.R[j] = Rs[j]; J.C[j] = Cs[j];
    J.tiles[j] = (Rs[j] / 32) * (Cs[j] / 32);
    total_tiles += J.tiles[j];
  }
  transpose_batch<<<total_tiles, tb, 0, stream>>>(J);

  // merged down projection: [S][2112] = Xb @ [wdq | wdkv | wkr]
  gemm_nt<float><<<dim3(17, 16), 256, 0, stream>>>(Xb, wt_down, dproj, DN, Hdim, Hdim, Hdim, DN, 1.f);
  rmsnorm_fused<<<dim3(S, 2), 256, 0, stream>>>(dproj, q_norm_w, k_norm_w, cqb, ckvb);

  // merged up projections
  gemm_nt<bf16><<<dim3(24, 16), 256, 0, stream>>>(cqb, wt_up1, up1, 3072, QC, QC, QC, 3072, 1.f);
  gemm_nt<bf16><<<dim3(8, 16), 256, 0, stream>>>(ckvb, wt_up2, up2, 1024, KVC, KVC, KVC, 1024, 1.f);

  build_qpack<<<(NH * S * 16 + NH * S * 8) / 256, 256, 0, stream>>>(up1, cosp, sinp, qpack);
  build_kpack<<<(NKV * S * 16 + S * 8) / 256, 256, 0, stream>>>(up2, dproj, cosp, sinp, kpack);
  transpose_b16<<<dim3(512 / 32, S / 32), tb, 0, stream>>>(up2 + 512, vt, S, 1024, S);

  // raw scores (all heads, one launch; 136 MB lower-tri -> L3-resident)
  gemm_scores<<<dim3(16, 16, NH), 256, 0, stream>>>(qpack, kpack, attn);
  // fused softmax + normalized-attn write + PV
  smpv<<<dim3(32, NH), 256, 0, stream>>>(attn, vt, ctxb);
  // output projection
  gemm_nt<float><<<dim3(16, 16), 256, 0, stream>>>(ctxb, wt_o, out0, Hdim, Hdim, Hdim, Hdim, Hdim, 1.f);
}

// Round 6
// 420.787 us; speedup vs baseline: 1.6357x; 1.0265x over previous
//
#include <hip/hip_runtime.h>
#include <stdint.h>

typedef __bf16 bf16;
typedef __bf16 bf16x8 __attribute__((ext_vector_type(8)));
typedef __bf16 bf16x4 __attribute__((ext_vector_type(4)));
typedef float f32x4 __attribute__((ext_vector_type(4)));

#define DEVFN static __device__ __forceinline__

constexpr int S = 2048, Hdim = 2048, NH = 16, NKV = 4, HD = 128, RHD = 64, QC = 1536, KVC = 512;
constexpr int QKD = HD + RHD;                 // 192
constexpr int DN = 2112;                      // merged down-proj width: QC + KVC + RHD
constexpr float RMS_EPS = 1e-6f;
constexpr float ATT_SCALE = 0.07216878364870323f;  // 1/sqrt(192)

// ---------------- reductions ----------------
DEVFN float wave_sum(float v) {
#pragma unroll
  for (int o = 32; o > 0; o >>= 1) v += __shfl_xor(v, o, 64);
  return v;
}
DEVFN float block_sum(float v) {
  __shared__ float red_s[4];
  v = wave_sum(v);
  int lane = threadIdx.x & 63, wid = threadIdx.x >> 6;
  if (lane == 0) red_s[wid] = v;
  __syncthreads();
  v = red_s[0] + red_s[1] + red_s[2] + red_s[3];
  __syncthreads();
  return v;
}

// ---------------- async global->LDS (16B per lane) ----------------
DEVFN void gload16(const bf16* g, bf16* l) {
  __builtin_amdgcn_global_load_lds(
      (const __attribute__((address_space(1))) uint32_t*)g,
      (__attribute__((address_space(3))) uint32_t*)l, 16, 0, 0);
}

// ---------------- async GEMM core (m97 structure): C = A[M,K] * Bt[N,K]^T ---
template <typename OT>
DEVFN void gemm_core_async(const bf16* __restrict__ A, const bf16* __restrict__ Bt,
                           OT* __restrict__ C, int N, int lda, int ldb, int ldc,
                           int m0, int n0, float scale, int kend) {
  __shared__ alignas(16) bf16 As[128 * 32];
  __shared__ alignas(16) bf16 Bs[128 * 32];
  const int t = threadIdx.x;
  const int lane = t & 63;
  const int wm = ((t >> 7) & 1) * 64;
  const int wn = ((t >> 6) & 1) * 64;
  const int lr = lane & 15;
  const int lk = (lane >> 4) * 8;
  const int srow = t >> 2;
  const int scol = (t & 3) * 8;
  const bf16* Ab = A + (size_t)(m0 + srow) * lda + scol;
  const bf16* Bb = Bt + (size_t)(n0 + srow) * ldb + scol;
  bf16* Al = As + t * 8;
  bf16* Bl = Bs + t * 8;

  f32x4 acc[4][4];
#pragma unroll
  for (int i = 0; i < 4; i++)
#pragma unroll
    for (int j = 0; j < 4; j++) { f32x4 z = {0.f, 0.f, 0.f, 0.f}; acc[i][j] = z; }

  for (int kk = 0; kk < kend; kk += 32) {
    gload16(Ab + kk, Al);
    gload16(Ab + (size_t)64 * lda + kk, Al + 2048);
    gload16(Bb + kk, Bl);
    gload16(Bb + (size_t)64 * ldb + kk, Bl + 2048);
    __syncthreads();
    bf16x8 a[4], b[4];
#pragma unroll
    for (int i = 0; i < 4; i++)
      a[i] = *reinterpret_cast<const bf16x8*>(&As[(wm + i * 16 + lr) * 32 + lk]);
#pragma unroll
    for (int i = 0; i < 4; i++)
      b[i] = *reinterpret_cast<const bf16x8*>(&Bs[(wn + i * 16 + lr) * 32 + lk]);
#pragma unroll
    for (int i = 0; i < 4; i++)
#pragma unroll
      for (int j = 0; j < 4; j++)
        acc[i][j] = __builtin_amdgcn_mfma_f32_16x16x32_bf16(a[i], b[j], acc[i][j], 0, 0, 0);
    __syncthreads();
  }
  const int orow = (lane >> 4) * 4;
#pragma unroll
  for (int i = 0; i < 4; i++) {
#pragma unroll
    for (int j = 0; j < 4; j++) {
      int col = n0 + wn + j * 16 + lr;
      if (col < N) {
#pragma unroll
        for (int q = 0; q < 4; q++) {
          int row = m0 + wm + i * 16 + orow + q;
          C[(size_t)row * ldc + col] = (OT)(acc[i][j][q] * scale);
        }
      }
    }
  }
}

template <typename OT>
__global__ __launch_bounds__(256) void gemm_nt(const bf16* __restrict__ A, const bf16* __restrict__ Bt,
                                               OT* __restrict__ C, int N, int K, int lda,
                                               int ldb, int ldc, float scale) {
  gemm_core_async<OT>(A, Bt, C, N, lda, ldb, ldc, blockIdx.y * 128, blockIdx.x * 128, scale, K);
}

// raw causal scores, all heads in one launch; writes only n0<=m0 blocks
__global__ __launch_bounds__(256) void gemm_scores(const bf16* __restrict__ qpack,
                                                   const bf16* __restrict__ kpack,
                                                   float* __restrict__ attn) {
  int h = blockIdx.z;
  int g = h >> 2;
  int m0 = blockIdx.y * 128, n0 = blockIdx.x * 128;
  if (n0 > m0) return;
  gemm_core_async<float>(qpack + (size_t)h * S * QKD, kpack + (size_t)g * S * QKD,
                         attn + (size_t)h * S * S, S, QKD, QKD, S, m0, n0, ATT_SCALE, QKD);
}

// ---------------- fused softmax + normalized-attn write + PV ----------------
// Balanced: each block = two 32-row strips (rows [32i,32i+32) and
// [2016-32i,2048-32i)) of one head -> constant work per block.
// Phase 1: single-pass online (m,l). Phase 2: BK=64 k-loop {normalize + write
// fp32 attn + bf16 P->LDS + V->LDS + lgkm-only barrier + MFMA}. Stores stay
// in flight across barriers (no vmcnt(0) drain). Tail zero-fill. 4 waves:
// wave (wm in {0,16}) x (wn in {0,64}), acc 1x4 frags.
__global__ __launch_bounds__(256) void smpv(float* __restrict__ attn,
                                            const bf16* __restrict__ vt,
                                            bf16* __restrict__ ctxb) {
  const int h = blockIdx.y;
  float* Ah = attn + (size_t)h * S * S;
  const bf16* Bt = vt + (size_t)(h >> 2) * HD * S;
  bf16* C = ctxb + h * HD;

  __shared__ alignas(16) bf16 As[32 * 72];
  __shared__ alignas(16) bf16 Bs[128 * 72];
  __shared__ float statm[32], statl[32];

  const int t = threadIdx.x;
  const int lane = t & 63;
  const int r0 = t >> 3;          // staging row 0..31
  const int part = t & 7;
  const int c0 = part * 8;
  const int wm = ((t >> 6) & 1) * 16;   // wave row: 0 or 16
  const int wn = (t >> 7) * 64;         // wave col: 0 or 64
  const int lr = lane & 15;
  const int lk = (lane >> 4) * 8;

  for (int sub = 0; sub < 2; ++sub) {
    const int m0 = sub ? (2016 - 32 * blockIdx.x) : (32 * blockIdx.x);
    const int kend = m0 + 32;       // causal: rows [m0,m0+32) need k <= m0+31
    const int rowg = m0 + r0;
    float* Arow = Ah + (size_t)rowg * S;

    // ---- phase 1: single-pass online row stats ----
    float m = -1e30f, l = 0.f;
    for (int c = c0; c < kend; c += 64) {
      float4 f0 = *reinterpret_cast<const float4*>(Arow + c);
      float4 f1 = *reinterpret_cast<const float4*>(Arow + c + 4);
      float v[8] = {f0.x, f0.y, f0.z, f0.w, f1.x, f1.y, f1.z, f1.w};
      float cm = -1e30f;
#pragma unroll
      for (int e = 0; e < 8; e++) cm = fmaxf(cm, (c + e <= rowg) ? v[e] : -1e30f);
      float nm = fmaxf(m, cm);
      float s = 0.f;
#pragma unroll
      for (int e = 0; e < 8; e++) s += (c + e <= rowg) ? __expf(v[e] - nm) : 0.f;
      l = l * __expf(m - nm) + s;
      m = nm;
    }
    // merge across the 8 threads of a row (lane bits 0..2)
#pragma unroll
    for (int o = 1; o <= 4; o <<= 1) {
      float mo = __shfl_xor(m, o, 64);
      float lo = __shfl_xor(l, o, 64);
      float M = fmaxf(m, mo);
      l = l * __expf(m - M) + lo * __expf(mo - M);
      m = M;
    }
    if (part == 0) { statm[r0] = m; statl[r0] = 1.0f / l; }
    __syncthreads();
    const float mr = statm[r0];
    const float invl = statl[r0];

    f32x4 acc[4];
#pragma unroll
    for (int j = 0; j < 4; j++) { f32x4 z = {0.f, 0.f, 0.f, 0.f}; acc[j] = z; }

    // ---- phase 2: normalize+write+PV, BK=64, lgkm-only barriers ----
    for (int kk = 0; kk < kend; kk += 64) {
      {
        float* p = Arow + kk + c0;
        float4 f0 = *reinterpret_cast<const float4*>(p);
        float4 f1 = *reinterpret_cast<const float4*>(p + 4);
        float v[8] = {f0.x, f0.y, f0.z, f0.w, f1.x, f1.y, f1.z, f1.w};
        bf16x8 vb;
#pragma unroll
        for (int e = 0; e < 8; e++) {
          float pe = (kk + c0 + e <= rowg) ? __expf(v[e] - mr) * invl : 0.f;
          v[e] = pe;
          vb[e] = (bf16)pe;
        }
        *reinterpret_cast<float4*>(p) = make_float4(v[0], v[1], v[2], v[3]);
        *reinterpret_cast<float4*>(p + 4) = make_float4(v[4], v[5], v[6], v[7]);
        *reinterpret_cast<bf16x8*>(&As[r0 * 72 + c0]) = vb;
      }
#pragma unroll
      for (int q = 0; q < 4; q++) {
        int cidx = q * 256 + t;
        int vr = cidx >> 3, vc = (cidx & 7) * 8;
        *reinterpret_cast<bf16x8*>(&Bs[vr * 72 + vc]) =
            *reinterpret_cast<const bf16x8*>(Bt + (size_t)vr * S + kk + vc);
      }
      asm volatile("s_waitcnt lgkmcnt(0)" ::: "memory");
      __builtin_amdgcn_s_barrier();
      bf16x8 a0 = *reinterpret_cast<const bf16x8*>(&As[(wm + lr) * 72 + lk]);
      bf16x8 a1 = *reinterpret_cast<const bf16x8*>(&As[(wm + lr) * 72 + 32 + lk]);
#pragma unroll
      for (int j = 0; j < 4; j++) {
        bf16x8 b0 = *reinterpret_cast<const bf16x8*>(&Bs[(wn + j * 16 + lr) * 72 + lk]);
        bf16x8 b1 = *reinterpret_cast<const bf16x8*>(&Bs[(wn + j * 16 + lr) * 72 + 32 + lk]);
        acc[j] = __builtin_amdgcn_mfma_f32_16x16x32_bf16(a0, b0, acc[j], 0, 0, 0);
        acc[j] = __builtin_amdgcn_mfma_f32_16x16x32_bf16(a1, b1, acc[j], 0, 0, 0);
      }
      asm volatile("s_waitcnt lgkmcnt(0)" ::: "memory");
      __builtin_amdgcn_s_barrier();
    }

    // ---- zero-fill causal tail [kend, S) ----
    const float4 zz = make_float4(0.f, 0.f, 0.f, 0.f);
    for (int c = kend + c0; c < S; c += 64) {
      *reinterpret_cast<float4*>(Arow + c) = zz;
      *reinterpret_cast<float4*>(Arow + c + 4) = zz;
    }

    // ---- epilogue: ctx write ----
    const int orow = (lane >> 4) * 4;
#pragma unroll
    for (int j = 0; j < 4; j++) {
      int col = wn + j * 16 + lr;
#pragma unroll
      for (int q = 0; q < 4; q++) {
        int row = m0 + wm + orow + q;
        C[(size_t)row * Hdim + col] = (bf16)acc[j][q];
      }
    }
  }
}

// ---------------- elementwise / reshape ----------------
__global__ __launch_bounds__(256) void cast_f32_bf16(const float* __restrict__ in,
                                                     bf16* __restrict__ out, int n8) {
  int i = blockIdx.x * 256 + threadIdx.x;
  if (i >= n8) return;
  float4 f0 = *reinterpret_cast<const float4*>(in + (size_t)i * 8);
  float4 f1 = *reinterpret_cast<const float4*>(in + (size_t)i * 8 + 4);
  bf16x8 v;
  v[0] = (bf16)f0.x; v[1] = (bf16)f0.y; v[2] = (bf16)f0.z; v[3] = (bf16)f0.w;
  v[4] = (bf16)f1.x; v[5] = (bf16)f1.y; v[6] = (bf16)f1.z; v[7] = (bf16)f1.w;
  *reinterpret_cast<bf16x8*>(out + (size_t)i * 8) = v;
}

// batched fp32 [R][C] -> bf16 [C][R] transposes (8 jobs, one dispatch)
struct TJobs {
  const float* src[8];
  bf16* dst[8];
  int R[8], C[8], tiles[8];
};

__global__ __launch_bounds__(256) void transpose_batch(TJobs J) {
  int tile = blockIdx.x;
  int j = 0;
  while (tile >= J.tiles[j]) { tile -= J.tiles[j]; ++j; }
  const int C = J.C[j], R = J.R[j];
  int tcn = C >> 5;
  int rb = (tile / tcn) * 32, cb = (tile % tcn) * 32;
  const float* in = J.src[j];
  bf16* out = J.dst[j];
  __shared__ float tl[32][33];
  int tx = threadIdx.x, ty = threadIdx.y;
#pragma unroll
  for (int q = 0; q < 32; q += 8)
    tl[ty + q][tx] = in[(size_t)(rb + ty + q) * C + cb + tx];
  __syncthreads();
#pragma unroll
  for (int q = 0; q < 32; q += 8)
    out[(size_t)(cb + ty + q) * R + rb + tx] = (bf16)tl[tx][ty + q];
}

// bf16 [R][C] (ld=ild) -> bf16 [C][R] (ld=old_)
__global__ __launch_bounds__(256) void transpose_b16(const bf16* __restrict__ in,
                                                     bf16* __restrict__ out, int R, int ild, int old_) {
  __shared__ float tl[32][33];
  int tx = threadIdx.x, ty = threadIdx.y;
  int cb = blockIdx.x * 32, rb = blockIdx.y * 32;
#pragma unroll
  for (int q = 0; q < 32; q += 8)
    tl[ty + q][tx] = (float)in[(size_t)(rb + ty + q) * ild + cb + tx];
  __syncthreads();
#pragma unroll
  for (int q = 0; q < 32; q += 8)
    out[(size_t)(cb + ty + q) * old_ + rb + tx] = (bf16)tl[tx][ty + q];
}

// fused RMSNorm for cq (y==0) and ckv (y==1) reading merged dproj
__global__ __launch_bounds__(256) void rmsnorm_fused(const float* __restrict__ dproj,
                                                     const float* __restrict__ qw,
                                                     const float* __restrict__ kw,
                                                     bf16* __restrict__ cqb,
                                                     bf16* __restrict__ ckvb) {
  int row = blockIdx.x;
  bool isq = (blockIdx.y == 0);
  int C = isq ? QC : KVC;
  const float* p = dproj + (size_t)row * DN + (isq ? 0 : QC);
  const float* w = isq ? qw : kw;
  bf16* out = (isq ? cqb : ckvb) + (size_t)row * C;
  float ss = 0.f;
  for (int i = threadIdx.x * 4; i < C; i += 1024) {
    float4 v = *reinterpret_cast<const float4*>(p + i);
    ss += v.x * v.x + v.y * v.y + v.z * v.z + v.w * v.w;
  }
  ss = block_sum(ss);
  float r = rsqrtf(ss / (float)C + RMS_EPS);
  for (int i = threadIdx.x * 4; i < C; i += 1024) {
    float4 v = *reinterpret_cast<const float4*>(p + i);
    float4 g = *reinterpret_cast<const float4*>(w + i);
    bf16x4 o;
    o[0] = (bf16)(v.x * r * g.x); o[1] = (bf16)(v.y * r * g.y);
    o[2] = (bf16)(v.z * r * g.z); o[3] = (bf16)(v.w * r * g.w);
    *reinterpret_cast<bf16x4*>(out + i) = o;
  }
}

// fused: pack qc slice of up1 into qpack + RoPE'd qr into qpack[...,128:]
__global__ __launch_bounds__(256) void build_qpack(const bf16* __restrict__ up1,
                                                   const float* __restrict__ cosp,
                                                   const float* __restrict__ sinp,
                                                   bf16* __restrict__ qpack) {
  int idx = blockIdx.x * 256 + threadIdx.x;
  const int P = NH * S * 16;  // 8-elem chunks of qc
  if (idx < P) {
    int d8 = idx & 15, s = (idx >> 4) & (S - 1), h = idx >> 15;
    int4 v = *reinterpret_cast<const int4*>(up1 + (size_t)s * 3072 + h * HD + d8 * 8);
    *reinterpret_cast<int4*>(qpack + ((size_t)h * S + s) * QKD + d8 * 8) = v;
  } else {
    int j = idx - P;
    int d0 = (j & 7) * 8, s = (j >> 3) & (S - 1), h = j >> 14;
    const bf16* xr = up1 + (size_t)s * 3072 + 2048 + h * RHD;
    bf16x8 xa = *reinterpret_cast<const bf16x8*>(xr + d0);
    bf16x8 xb = *reinterpret_cast<const bf16x8*>(xr + (d0 ^ 32));
    float sign = (d0 < 32) ? -1.f : 1.f;
    const float* cr = cosp + s * RHD + d0;
    const float* sr = sinp + s * RHD + d0;
    bf16x8 o;
#pragma unroll
    for (int i = 0; i < 8; i++)
      o[i] = (bf16)((float)xa[i] * cr[i] + sign * (float)xb[i] * sr[i]);
    *reinterpret_cast<bf16x8*>(qpack + ((size_t)h * S + s) * QKD + HD + d0) = o;
  }
}

// fused: pack kc slice of up2 into kpack + RoPE'd kr (from dproj col 2048) into all groups
__global__ __launch_bounds__(256) void build_kpack(const bf16* __restrict__ up2,
                                                   const float* __restrict__ dproj,
                                                   const float* __restrict__ cosp,
                                                   const float* __restrict__ sinp,
                                                   bf16* __restrict__ kpack) {
  int idx = blockIdx.x * 256 + threadIdx.x;
  const int P = NKV * S * 16;
  if (idx < P) {
    int d8 = idx & 15, s = (idx >> 4) & (S - 1), g = idx >> 15;
    int4 v = *reinterpret_cast<const int4*>(up2 + (size_t)s * 1024 + g * HD + d8 * 8);
    *reinterpret_cast<int4*>(kpack + ((size_t)g * S + s) * QKD + d8 * 8) = v;
  } else {
    int j = idx - P;
    int d0 = (j & 7) * 8, s = j >> 3;
    const float* xr = dproj + (size_t)s * DN + 2048;
    float4 a0 = *reinterpret_cast<const float4*>(xr + d0);
    float4 a1 = *reinterpret_cast<const float4*>(xr + d0 + 4);
    float4 b0 = *reinterpret_cast<const float4*>(xr + (d0 ^ 32));
    float4 b1 = *reinterpret_cast<const float4*>(xr + (d0 ^ 32) + 4);
    float sign = (d0 < 32) ? -1.f : 1.f;
    const float* cr = cosp + s * RHD + d0;
    const float* sr = sinp + s * RHD + d0;
    float xa[8] = {a0.x, a0.y, a0.z, a0.w, a1.x, a1.y, a1.z, a1.w};
    float xb[8] = {b0.x, b0.y, b0.z, b0.w, b1.x, b1.y, b1.z, b1.w};
    bf16x8 o;
#pragma unroll
    for (int i = 0; i < 8; i++)
      o[i] = (bf16)(xa[i] * cr[i] + sign * xb[i] * sr[i]);
#pragma unroll
    for (int g = 0; g < NKV; g++)
      *reinterpret_cast<bf16x8*>(kpack + ((size_t)g * S + s) * QKD + HD + d0) = o;
  }
}

// ---------------- launcher ----------------
extern "C" void kernel_launch(void* const* d_in, const int* in_sizes, int n_in, void* d_out,
                              int out_size, void* d_ws, size_t ws_size, hipStream_t stream) {
  const float* Xf = (const float*)d_in[0];
  const float* cosp = (const float*)d_in[1];
  const float* sinp = (const float*)d_in[2];
  const float* w_down_q = (const float*)d_in[4];
  const float* w_up_q = (const float*)d_in[5];
  const float* w_qr = (const float*)d_in[6];
  const float* w_down_kv = (const float*)d_in[7];
  const float* w_up_k = (const float*)d_in[8];
  const float* w_up_v = (const float*)d_in[9];
  const float* w_kr = (const float*)d_in[10];
  const float* w_o = (const float*)d_in[11];
  const float* q_norm_w = (const float*)d_in[12];
  const float* k_norm_w = (const float*)d_in[13];

  float* out0 = (float*)d_out;
  float* attn = out0 + (size_t)S * Hdim;

  char* base = (char*)d_ws;
  size_t off = 0;
  auto carve = [&](size_t bytes) -> void* {
    void* p = base + off;
    off += (bytes + 255) & ~(size_t)255;
    return p;
  };
  bf16* Xb      = (bf16*)carve((size_t)S * Hdim * 2);
  bf16* wt_down = (bf16*)carve((size_t)2176 * 2048 * 2);  // [2112(+pad)][2048]
  bf16* wt_up1  = (bf16*)carve((size_t)3072 * QC * 2);    // [3072][1536]
  bf16* wt_up2  = (bf16*)carve((size_t)1024 * KVC * 2);   // [1024][512]
  bf16* wt_o    = (bf16*)carve((size_t)Hdim * Hdim * 2);
  float* dproj  = (float*)carve((size_t)S * DN * 4);      // [2048][2112]
  bf16* cqb     = (bf16*)carve((size_t)S * QC * 2);
  bf16* ckvb    = (bf16*)carve((size_t)S * KVC * 2);
  bf16* up1     = (bf16*)carve((size_t)S * 3072 * 2);     // [s][qc 0:2048 | qr 2048:3072]
  bf16* up2     = (bf16*)carve((size_t)S * 1024 * 2);     // [s][kc 0:512 | v 512:1024]
  bf16* qpack   = (bf16*)carve((size_t)NH * S * QKD * 2);
  bf16* kpack   = (bf16*)carve((size_t)NKV * S * QKD * 2);
  bf16* vt      = (bf16*)carve((size_t)NKV * HD * S * 2);
  bf16* ctxb    = (bf16*)carve((size_t)S * Hdim * 2);
  (void)in_sizes; (void)n_in; (void)out_size; (void)ws_size;

  dim3 tb(32, 8);
  cast_f32_bf16<<<S * Hdim / 8 / 256, 256, 0, stream>>>(Xf, Xb, S * Hdim / 8);

  TJobs J;
  const float* srcs[8] = {w_down_q, w_down_kv, w_kr, w_up_q, w_qr, w_up_k, w_up_v, w_o};
  bf16* dsts[8] = {wt_down, wt_down + (size_t)QC * 2048, wt_down + (size_t)2048 * 2048,
                   wt_up1, wt_up1 + (size_t)2048 * QC, wt_up2, wt_up2 + (size_t)512 * KVC, wt_o};
  int Rs[8] = {2048, 2048, 2048, 1536, 1536, 512, 512, 2048};
  int Cs[8] = {1536, 512, 64, 2048, 1024, 512, 512, 2048};
  int total_tiles = 0;
  for (int j = 0; j < 8; j++) {
    J.src[j] = srcs[j]; J.dst[j] = dsts[j]; J.R[j] = Rs[j]; J.C[j] = Cs[j];
    J.tiles[j] = (Rs[j] / 32) * (Cs[j] / 32);
    total_tiles += J.tiles[j];
  }
  transpose_batch<<<total_tiles, tb, 0, stream>>>(J);

  // merged down projection: [S][2112] = Xb @ [wdq | wdkv | wkr]
  gemm_nt<float><<<dim3(17, 16), 256, 0, stream>>>(Xb, wt_down, dproj, DN, Hdim, Hdim, Hdim, DN, 1.f);
  rmsnorm_fused<<<dim3(S, 2), 256, 0, stream>>>(dproj, q_norm_w, k_norm_w, cqb, ckvb);

  // merged up projections
  gemm_nt<bf16><<<dim3(24, 16), 256, 0, stream>>>(cqb, wt_up1, up1, 3072, QC, QC, QC, 3072, 1.f);
  gemm_nt<bf16><<<dim3(8, 16), 256, 0, stream>>>(ckvb, wt_up2, up2, 1024, KVC, KVC, KVC, 1024, 1.f);

  build_qpack<<<(NH * S * 16 + NH * S * 8) / 256, 256, 0, stream>>>(up1, cosp, sinp, qpack);
  build_kpack<<<(NKV * S * 16 + S * 8) / 256, 256, 0, stream>>>(up2, dproj, cosp, sinp, kpack);
  transpose_b16<<<dim3(512 / 32, S / 32), tb, 0, stream>>>(up2 + 512, vt, S, 1024, S);

  // raw scores (all heads, one launch)
  gemm_scores<<<dim3(16, 16, NH), 256, 0, stream>>>(qpack, kpack, attn);
  // fused softmax + normalized-attn write + PV (balanced strip pairs)
  smpv<<<dim3(32, NH), 256, 0, stream>>>(attn, vt, ctxb);
  // output projection
  gemm_nt<float><<<dim3(16, 16), 256, 0, stream>>>(ctxb, wt_o, out0, Hdim, Hdim, Hdim, Hdim, Hdim, 1.f);
}

// Round 7
// 407.318 us; speedup vs baseline: 1.6898x; 1.0331x over previous
//
#include <hip/hip_runtime.h>
#include <stdint.h>

typedef __bf16 bf16;
typedef __bf16 bf16x8 __attribute__((ext_vector_type(8)));
typedef __bf16 bf16x4 __attribute__((ext_vector_type(4)));
typedef float f32x4 __attribute__((ext_vector_type(4)));

#define DEVFN static __device__ __forceinline__

constexpr int S = 2048, Hdim = 2048, NH = 16, NKV = 4, HD = 128, RHD = 64, QC = 1536, KVC = 512;
constexpr int QKD = HD + RHD;                 // 192
constexpr int DN = 2112;                      // merged down-proj width: QC + KVC + RHD
constexpr float RMS_EPS = 1e-6f;
constexpr float ATT_SCALE = 0.07216878364870323f;  // 1/sqrt(192)

// ---------------- reductions ----------------
DEVFN float wave_sum(float v) {
#pragma unroll
  for (int o = 32; o > 0; o >>= 1) v += __shfl_xor(v, o, 64);
  return v;
}
DEVFN float block_sum(float v) {
  __shared__ float red_s[4];
  v = wave_sum(v);
  int lane = threadIdx.x & 63, wid = threadIdx.x >> 6;
  if (lane == 0) red_s[wid] = v;
  __syncthreads();
  v = red_s[0] + red_s[1] + red_s[2] + red_s[3];
  __syncthreads();
  return v;
}

// ---------------- async global->LDS (16B per lane) ----------------
DEVFN void gload16(const bf16* g, bf16* l) {
  __builtin_amdgcn_global_load_lds(
      (const __attribute__((address_space(1))) uint32_t*)g,
      (__attribute__((address_space(3))) uint32_t*)l, 16, 0, 0);
}

// ---------------- async GEMM core (m97 structure): C = A[M,K] * Bt[N,K]^T ---
template <typename OT>
DEVFN void gemm_core_async(const bf16* __restrict__ A, const bf16* __restrict__ Bt,
                           OT* __restrict__ C, int N, int lda, int ldb, int ldc,
                           int m0, int n0, float scale, int kend) {
  __shared__ alignas(16) bf16 As[128 * 32];
  __shared__ alignas(16) bf16 Bs[128 * 32];
  const int t = threadIdx.x;
  const int lane = t & 63;
  const int wm = ((t >> 7) & 1) * 64;
  const int wn = ((t >> 6) & 1) * 64;
  const int lr = lane & 15;
  const int lk = (lane >> 4) * 8;
  const int srow = t >> 2;
  const int scol = (t & 3) * 8;
  const bf16* Ab = A + (size_t)(m0 + srow) * lda + scol;
  const bf16* Bb = Bt + (size_t)(n0 + srow) * ldb + scol;
  bf16* Al = As + t * 8;
  bf16* Bl = Bs + t * 8;

  f32x4 acc[4][4];
#pragma unroll
  for (int i = 0; i < 4; i++)
#pragma unroll
    for (int j = 0; j < 4; j++) { f32x4 z = {0.f, 0.f, 0.f, 0.f}; acc[i][j] = z; }

  for (int kk = 0; kk < kend; kk += 32) {
    gload16(Ab + kk, Al);
    gload16(Ab + (size_t)64 * lda + kk, Al + 2048);
    gload16(Bb + kk, Bl);
    gload16(Bb + (size_t)64 * ldb + kk, Bl + 2048);
    __syncthreads();
    bf16x8 a[4], b[4];
#pragma unroll
    for (int i = 0; i < 4; i++)
      a[i] = *reinterpret_cast<const bf16x8*>(&As[(wm + i * 16 + lr) * 32 + lk]);
#pragma unroll
    for (int i = 0; i < 4; i++)
      b[i] = *reinterpret_cast<const bf16x8*>(&Bs[(wn + i * 16 + lr) * 32 + lk]);
#pragma unroll
    for (int i = 0; i < 4; i++)
#pragma unroll
      for (int j = 0; j < 4; j++)
        acc[i][j] = __builtin_amdgcn_mfma_f32_16x16x32_bf16(a[i], b[j], acc[i][j], 0, 0, 0);
    __syncthreads();
  }
  const int orow = (lane >> 4) * 4;
#pragma unroll
  for (int i = 0; i < 4; i++) {
#pragma unroll
    for (int j = 0; j < 4; j++) {
      int col = n0 + wn + j * 16 + lr;
      if (col < N) {
#pragma unroll
        for (int q = 0; q < 4; q++) {
          int row = m0 + wm + i * 16 + orow + q;
          C[(size_t)row * ldc + col] = (OT)(acc[i][j][q] * scale);
        }
      }
    }
  }
}

template <typename OT>
__global__ __launch_bounds__(256) void gemm_nt(const bf16* __restrict__ A, const bf16* __restrict__ Bt,
                                               OT* __restrict__ C, int N, int K, int lda,
                                               int ldb, int ldc, float scale) {
  gemm_core_async<OT>(A, Bt, C, N, lda, ldb, ldc, blockIdx.y * 128, blockIdx.x * 128, scale, K);
}

// raw causal scores, all heads in one launch; writes only n0<=m0 blocks
__global__ __launch_bounds__(256) void gemm_scores(const bf16* __restrict__ qpack,
                                                   const bf16* __restrict__ kpack,
                                                   float* __restrict__ attn) {
  int h = blockIdx.z;
  int g = h >> 2;
  int m0 = blockIdx.y * 128, n0 = blockIdx.x * 128;
  if (n0 > m0) return;
  gemm_core_async<float>(qpack + (size_t)h * S * QKD, kpack + (size_t)g * S * QKD,
                         attn + (size_t)h * S * S, S, QKD, QKD, S, m0, n0, ATT_SCALE, QKD);
}

// ---------------- per-row softmax stats (m, 1/l), one wave per row ----------
__global__ __launch_bounds__(256) void attn_stats(const float* __restrict__ attn,
                                                  float* __restrict__ stats) {
  const int h = blockIdx.y;
  const int wid = threadIdx.x >> 6, lane = threadIdx.x & 63;
  const int s = blockIdx.x * 4 + wid;
  const float* row = attn + ((size_t)h * S + s) * S;
  const int n = s + 1;
  float m = -1e30f, l = 0.f;
  for (int c = lane * 4; c < n; c += 256) {
    float4 v = *reinterpret_cast<const float4*>(row + c);
    float e[4] = {v.x, v.y, v.z, v.w};
    float cm = -1e30f;
#pragma unroll
    for (int u = 0; u < 4; u++) cm = fmaxf(cm, (c + u <= s) ? e[u] : -1e30f);
    float nm = fmaxf(m, cm);
    float ss = 0.f;
#pragma unroll
    for (int u = 0; u < 4; u++) ss += (c + u <= s) ? __expf(e[u] - nm) : 0.f;
    l = l * __expf(m - nm) + ss;
    m = nm;
  }
#pragma unroll
  for (int o = 1; o < 64; o <<= 1) {
    float mo = __shfl_xor(m, o, 64);
    float lo = __shfl_xor(l, o, 64);
    float M = fmaxf(m, mo);
    l = l * __expf(m - M) + lo * __expf(mo - M);
    m = M;
  }
  if (lane == 0) {
    stats[((size_t)h * S + s) * 2] = m;
    stats[((size_t)h * S + s) * 2 + 1] = 1.0f / l;
  }
}

// ---------------- fused normalize + attn write + PV ----------------
// Balanced: block = two 16-row strips (rows [16i,16i+16) and [2032-16i, ...))
// of one head. BK=128 k-loop: {normalize+write fp32 attn, bf16 P->LDS,
// V->LDS, lgkm-only barrier, MFMA}. Stores stay in flight across barriers.
// 4 waves, each owns 32 output cols. Grid (64, NH) = 1024 blocks.
__global__ __launch_bounds__(256) void smpv(float* __restrict__ attn,
                                            const float* __restrict__ stats,
                                            const bf16* __restrict__ vt,
                                            bf16* __restrict__ ctxb) {
  const int h = blockIdx.y;
  float* Ah = attn + (size_t)h * S * S;
  const bf16* Bt = vt + (size_t)(h >> 2) * HD * S;
  bf16* C = ctxb + h * HD;

  __shared__ alignas(16) bf16 As[16 * 136];
  __shared__ alignas(16) bf16 Bs[128 * 136];

  const int t = threadIdx.x;
  const int lane = t & 63;
  const int wid = t >> 6;
  const int r0 = t >> 4;         // staging row 0..15
  const int c0 = (t & 15) * 8;   // staging col 0..120
  const int wn = wid * 32;       // wave's output-col base
  const int lr = lane & 15;
  const int lk = (lane >> 4) * 8;

  for (int sub = 0; sub < 2; ++sub) {
    const int m0 = sub ? (2032 - 16 * blockIdx.x) : (16 * blockIdx.x);
    const int kend = m0 + 16;                 // rows [m0,m0+16) need k <= m0+15
    const int kup = (kend + 127) & ~127;      // round up to written 128-block
    const int rowg = m0 + r0;
    float* Arow = Ah + (size_t)rowg * S;
    const float mr = stats[((size_t)h * S + rowg) * 2];
    const float invl = stats[((size_t)h * S + rowg) * 2 + 1];

    f32x4 acc[2];
#pragma unroll
    for (int j = 0; j < 2; j++) { f32x4 z = {0.f, 0.f, 0.f, 0.f}; acc[j] = z; }

    for (int kk = 0; kk < kup; kk += 128) {
      // A: read raw scores, normalize (masked), write back fp32, stash bf16
      {
        float* p = Arow + kk + c0;
        float4 f0 = *reinterpret_cast<const float4*>(p);
        float4 f1 = *reinterpret_cast<const float4*>(p + 4);
        float v[8] = {f0.x, f0.y, f0.z, f0.w, f1.x, f1.y, f1.z, f1.w};
        bf16x8 vb;
#pragma unroll
        for (int e = 0; e < 8; e++) {
          float pe = (kk + c0 + e <= rowg) ? __expf(v[e] - mr) * invl : 0.f;
          v[e] = pe;
          vb[e] = (bf16)pe;
        }
        *reinterpret_cast<float4*>(p) = make_float4(v[0], v[1], v[2], v[3]);
        *reinterpret_cast<float4*>(p + 4) = make_float4(v[4], v[5], v[6], v[7]);
        *reinterpret_cast<bf16x8*>(&As[r0 * 136 + c0]) = vb;
      }
      // V: 128 rows x 128 cols, 8 chunks per thread
#pragma unroll
      for (int q = 0; q < 8; q++) {
        int cidx = q * 256 + t;
        int vr = cidx >> 4, vc = (cidx & 15) * 8;
        *reinterpret_cast<bf16x8*>(&Bs[vr * 136 + vc]) =
            *reinterpret_cast<const bf16x8*>(Bt + (size_t)vr * S + kk + vc);
      }
      asm volatile("s_waitcnt lgkmcnt(0)" ::: "memory");
      __builtin_amdgcn_s_barrier();
      bf16x8 a[4];
#pragma unroll
      for (int ks = 0; ks < 4; ks++)
        a[ks] = *reinterpret_cast<const bf16x8*>(&As[lr * 136 + ks * 32 + lk]);
#pragma unroll
      for (int j = 0; j < 2; j++) {
#pragma unroll
        for (int ks = 0; ks < 4; ks++) {
          bf16x8 b = *reinterpret_cast<const bf16x8*>(&Bs[(wn + j * 16 + lr) * 136 + ks * 32 + lk]);
          acc[j] = __builtin_amdgcn_mfma_f32_16x16x32_bf16(a[ks], b, acc[j], 0, 0, 0);
        }
      }
      asm volatile("s_waitcnt lgkmcnt(0)" ::: "memory");
      __builtin_amdgcn_s_barrier();
    }

    // zero-fill causal tail [kup, S)
    const float4 zz = make_float4(0.f, 0.f, 0.f, 0.f);
    for (int kk = kup; kk < S; kk += 128) {
      float* p = Arow + kk + c0;
      *reinterpret_cast<float4*>(p) = zz;
      *reinterpret_cast<float4*>(p + 4) = zz;
    }

    // epilogue: ctx write (16 rows x 128 cols)
    const int orow = (lane >> 4) * 4;
#pragma unroll
    for (int j = 0; j < 2; j++) {
      int col = wn + j * 16 + lr;
#pragma unroll
      for (int q = 0; q < 4; q++) {
        int row = m0 + orow + q;
        C[(size_t)row * Hdim + col] = (bf16)acc[j][q];
      }
    }
  }
}

// ---------------- elementwise / reshape ----------------
__global__ __launch_bounds__(256) void cast_f32_bf16(const float* __restrict__ in,
                                                     bf16* __restrict__ out, int n8) {
  int i = blockIdx.x * 256 + threadIdx.x;
  if (i >= n8) return;
  float4 f0 = *reinterpret_cast<const float4*>(in + (size_t)i * 8);
  float4 f1 = *reinterpret_cast<const float4*>(in + (size_t)i * 8 + 4);
  bf16x8 v;
  v[0] = (bf16)f0.x; v[1] = (bf16)f0.y; v[2] = (bf16)f0.z; v[3] = (bf16)f0.w;
  v[4] = (bf16)f1.x; v[5] = (bf16)f1.y; v[6] = (bf16)f1.z; v[7] = (bf16)f1.w;
  *reinterpret_cast<bf16x8*>(out + (size_t)i * 8) = v;
}

// batched fp32 [R][C] -> bf16 [C][R] transposes (8 jobs, one dispatch)
struct TJobs {
  const float* src[8];
  bf16* dst[8];
  int R[8], C[8], tiles[8];
};

__global__ __launch_bounds__(256) void transpose_batch(TJobs J) {
  int tile = blockIdx.x;
  int j = 0;
  while (tile >= J.tiles[j]) { tile -= J.tiles[j]; ++j; }
  const int C = J.C[j], R = J.R[j];
  int tcn = C >> 5;
  int rb = (tile / tcn) * 32, cb = (tile % tcn) * 32;
  const float* in = J.src[j];
  bf16* out = J.dst[j];
  __shared__ float tl[32][33];
  int tx = threadIdx.x, ty = threadIdx.y;
#pragma unroll
  for (int q = 0; q < 32; q += 8)
    tl[ty + q][tx] = in[(size_t)(rb + ty + q) * C + cb + tx];
  __syncthreads();
#pragma unroll
  for (int q = 0; q < 32; q += 8)
    out[(size_t)(cb + ty + q) * R + rb + tx] = (bf16)tl[tx][ty + q];
}

// bf16 [R][C] (ld=ild) -> bf16 [C][R] (ld=old_)
__global__ __launch_bounds__(256) void transpose_b16(const bf16* __restrict__ in,
                                                     bf16* __restrict__ out, int R, int ild, int old_) {
  __shared__ float tl[32][33];
  int tx = threadIdx.x, ty = threadIdx.y;
  int cb = blockIdx.x * 32, rb = blockIdx.y * 32;
#pragma unroll
  for (int q = 0; q < 32; q += 8)
    tl[ty + q][tx] = (float)in[(size_t)(rb + ty + q) * ild + cb + tx];
  __syncthreads();
#pragma unroll
  for (int q = 0; q < 32; q += 8)
    out[(size_t)(cb + ty + q) * old_ + rb + tx] = (bf16)tl[tx][ty + q];
}

// fused RMSNorm for cq (y==0) and ckv (y==1) reading merged dproj
__global__ __launch_bounds__(256) void rmsnorm_fused(const float* __restrict__ dproj,
                                                     const float* __restrict__ qw,
                                                     const float* __restrict__ kw,
                                                     bf16* __restrict__ cqb,
                                                     bf16* __restrict__ ckvb) {
  int row = blockIdx.x;
  bool isq = (blockIdx.y == 0);
  int C = isq ? QC : KVC;
  const float* p = dproj + (size_t)row * DN + (isq ? 0 : QC);
  const float* w = isq ? qw : kw;
  bf16* out = (isq ? cqb : ckvb) + (size_t)row * C;
  float ss = 0.f;
  for (int i = threadIdx.x * 4; i < C; i += 1024) {
    float4 v = *reinterpret_cast<const float4*>(p + i);
    ss += v.x * v.x + v.y * v.y + v.z * v.z + v.w * v.w;
  }
  ss = block_sum(ss);
  float r = rsqrtf(ss / (float)C + RMS_EPS);
  for (int i = threadIdx.x * 4; i < C; i += 1024) {
    float4 v = *reinterpret_cast<const float4*>(p + i);
    float4 g = *reinterpret_cast<const float4*>(w + i);
    bf16x4 o;
    o[0] = (bf16)(v.x * r * g.x); o[1] = (bf16)(v.y * r * g.y);
    o[2] = (bf16)(v.z * r * g.z); o[3] = (bf16)(v.w * r * g.w);
    *reinterpret_cast<bf16x4*>(out + i) = o;
  }
}

// fused: pack qc slice of up1 into qpack + RoPE'd qr into qpack[...,128:]
__global__ __launch_bounds__(256) void build_qpack(const bf16* __restrict__ up1,
                                                   const float* __restrict__ cosp,
                                                   const float* __restrict__ sinp,
                                                   bf16* __restrict__ qpack) {
  int idx = blockIdx.x * 256 + threadIdx.x;
  const int P = NH * S * 16;  // 8-elem chunks of qc
  if (idx < P) {
    int d8 = idx & 15, s = (idx >> 4) & (S - 1), h = idx >> 15;
    int4 v = *reinterpret_cast<const int4*>(up1 + (size_t)s * 3072 + h * HD + d8 * 8);
    *reinterpret_cast<int4*>(qpack + ((size_t)h * S + s) * QKD + d8 * 8) = v;
  } else {
    int j = idx - P;
    int d0 = (j & 7) * 8, s = (j >> 3) & (S - 1), h = j >> 14;
    const bf16* xr = up1 + (size_t)s * 3072 + 2048 + h * RHD;
    bf16x8 xa = *reinterpret_cast<const bf16x8*>(xr + d0);
    bf16x8 xb = *reinterpret_cast<const bf16x8*>(xr + (d0 ^ 32));
    float sign = (d0 < 32) ? -1.f : 1.f;
    const float* cr = cosp + s * RHD + d0;
    const float* sr = sinp + s * RHD + d0;
    bf16x8 o;
#pragma unroll
    for (int i = 0; i < 8; i++)
      o[i] = (bf16)((float)xa[i] * cr[i] + sign * (float)xb[i] * sr[i]);
    *reinterpret_cast<bf16x8*>(qpack + ((size_t)h * S + s) * QKD + HD + d0) = o;
  }
}

// fused: pack kc slice of up2 into kpack + RoPE'd kr (from dproj col 2048) into all groups
__global__ __launch_bounds__(256) void build_kpack(const bf16* __restrict__ up2,
                                                   const float* __restrict__ dproj,
                                                   const float* __restrict__ cosp,
                                                   const float* __restrict__ sinp,
                                                   bf16* __restrict__ kpack) {
  int idx = blockIdx.x * 256 + threadIdx.x;
  const int P = NKV * S * 16;
  if (idx < P) {
    int d8 = idx & 15, s = (idx >> 4) & (S - 1), g = idx >> 15;
    int4 v = *reinterpret_cast<const int4*>(up2 + (size_t)s * 1024 + g * HD + d8 * 8);
    *reinterpret_cast<int4*>(kpack + ((size_t)g * S + s) * QKD + d8 * 8) = v;
  } else {
    int j = idx - P;
    int d0 = (j & 7) * 8, s = j >> 3;
    const float* xr = dproj + (size_t)s * DN + 2048;
    float4 a0 = *reinterpret_cast<const float4*>(xr + d0);
    float4 a1 = *reinterpret_cast<const float4*>(xr + d0 + 4);
    float4 b0 = *reinterpret_cast<const float4*>(xr + (d0 ^ 32));
    float4 b1 = *reinterpret_cast<const float4*>(xr + (d0 ^ 32) + 4);
    float sign = (d0 < 32) ? -1.f : 1.f;
    const float* cr = cosp + s * RHD + d0;
    const float* sr = sinp + s * RHD + d0;
    float xa[8] = {a0.x, a0.y, a0.z, a0.w, a1.x, a1.y, a1.z, a1.w};
    float xb[8] = {b0.x, b0.y, b0.z, b0.w, b1.x, b1.y, b1.z, b1.w};
    bf16x8 o;
#pragma unroll
    for (int i = 0; i < 8; i++)
      o[i] = (bf16)(xa[i] * cr[i] + sign * xb[i] * sr[i]);
#pragma unroll
    for (int g = 0; g < NKV; g++)
      *reinterpret_cast<bf16x8*>(kpack + ((size_t)g * S + s) * QKD + HD + d0) = o;
  }
}

// ---------------- launcher ----------------
extern "C" void kernel_launch(void* const* d_in, const int* in_sizes, int n_in, void* d_out,
                              int out_size, void* d_ws, size_t ws_size, hipStream_t stream) {
  const float* Xf = (const float*)d_in[0];
  const float* cosp = (const float*)d_in[1];
  const float* sinp = (const float*)d_in[2];
  const float* w_down_q = (const float*)d_in[4];
  const float* w_up_q = (const float*)d_in[5];
  const float* w_qr = (const float*)d_in[6];
  const float* w_down_kv = (const float*)d_in[7];
  const float* w_up_k = (const float*)d_in[8];
  const float* w_up_v = (const float*)d_in[9];
  const float* w_kr = (const float*)d_in[10];
  const float* w_o = (const float*)d_in[11];
  const float* q_norm_w = (const float*)d_in[12];
  const float* k_norm_w = (const float*)d_in[13];

  float* out0 = (float*)d_out;
  float* attn = out0 + (size_t)S * Hdim;

  char* base = (char*)d_ws;
  size_t off = 0;
  auto carve = [&](size_t bytes) -> void* {
    void* p = base + off;
    off += (bytes + 255) & ~(size_t)255;
    return p;
  };
  bf16* Xb      = (bf16*)carve((size_t)S * Hdim * 2);
  bf16* wt_down = (bf16*)carve((size_t)2176 * 2048 * 2);  // [2112(+pad)][2048]
  bf16* wt_up1  = (bf16*)carve((size_t)3072 * QC * 2);    // [3072][1536]
  bf16* wt_up2  = (bf16*)carve((size_t)1024 * KVC * 2);   // [1024][512]
  bf16* wt_o    = (bf16*)carve((size_t)Hdim * Hdim * 2);
  float* dproj  = (float*)carve((size_t)S * DN * 4);      // [2048][2112]
  bf16* cqb     = (bf16*)carve((size_t)S * QC * 2);
  bf16* ckvb    = (bf16*)carve((size_t)S * KVC * 2);
  bf16* up1     = (bf16*)carve((size_t)S * 3072 * 2);     // [s][qc 0:2048 | qr 2048:3072]
  bf16* up2     = (bf16*)carve((size_t)S * 1024 * 2);     // [s][kc 0:512 | v 512:1024]
  bf16* qpack   = (bf16*)carve((size_t)NH * S * QKD * 2);
  bf16* kpack   = (bf16*)carve((size_t)NKV * S * QKD * 2);
  bf16* vt      = (bf16*)carve((size_t)NKV * HD * S * 2);
  bf16* ctxb    = (bf16*)carve((size_t)S * Hdim * 2);
  float* stats  = (float*)carve((size_t)NH * S * 2 * 4);  // per-row (m, 1/l)
  (void)in_sizes; (void)n_in; (void)out_size; (void)ws_size;

  dim3 tb(32, 8);
  cast_f32_bf16<<<S * Hdim / 8 / 256, 256, 0, stream>>>(Xf, Xb, S * Hdim / 8);

  TJobs J;
  const float* srcs[8] = {w_down_q, w_down_kv, w_kr, w_up_q, w_qr, w_up_k, w_up_v, w_o};
  bf16* dsts[8] = {wt_down, wt_down + (size_t)QC * 2048, wt_down + (size_t)2048 * 2048,
                   wt_up1, wt_up1 + (size_t)2048 * QC, wt_up2, wt_up2 + (size_t)512 * KVC, wt_o};
  int Rs[8] = {2048, 2048, 2048, 1536, 1536, 512, 512, 2048};
  int Cs[8] = {1536, 512, 64, 2048, 1024, 512, 512, 2048};
  int total_tiles = 0;
  for (int j = 0; j < 8; j++) {
    J.src[j] = srcs[j]; J.dst[j] = dsts[j]; J.R[j] = Rs[j]; J.C[j] = Cs[j];
    J.tiles[j] = (Rs[j] / 32) * (Cs[j] / 32);
    total_tiles += J.tiles[j];
  }
  transpose_batch<<<total_tiles, tb, 0, stream>>>(J);

  // merged down projection: [S][2112] = Xb @ [wdq | wdkv | wkr]
  gemm_nt<float><<<dim3(17, 16), 256, 0, stream>>>(Xb, wt_down, dproj, DN, Hdim, Hdim, Hdim, DN, 1.f);
  rmsnorm_fused<<<dim3(S, 2), 256, 0, stream>>>(dproj, q_norm_w, k_norm_w, cqb, ckvb);

  // merged up projections
  gemm_nt<bf16><<<dim3(24, 16), 256, 0, stream>>>(cqb, wt_up1, up1, 3072, QC, QC, QC, 3072, 1.f);
  gemm_nt<bf16><<<dim3(8, 16), 256, 0, stream>>>(ckvb, wt_up2, up2, 1024, KVC, KVC, KVC, 1024, 1.f);

  build_qpack<<<(NH * S * 16 + NH * S * 8) / 256, 256, 0, stream>>>(up1, cosp, sinp, qpack);
  build_kpack<<<(NKV * S * 16 + S * 8) / 256, 256, 0, stream>>>(up2, dproj, cosp, sinp, kpack);
  transpose_b16<<<dim3(512 / 32, S / 32), tb, 0, stream>>>(up2 + 512, vt, S, 1024, S);

  // raw scores (all heads, one launch)
  gemm_scores<<<dim3(16, 16, NH), 256, 0, stream>>>(qpack, kpack, attn);
  // per-row softmax stats (one wave per row, fully parallel)
  attn_stats<<<dim3(S / 4, NH), 256, 0, stream>>>(attn, stats);
  // fused normalize + attn write + PV (16-row balanced pairs, 1024 blocks)
  smpv<<<dim3(64, NH), 256, 0, stream>>>(attn, stats, vt, ctxb);
  // output projection
  gemm_nt<float><<<dim3(16, 16), 256, 0, stream>>>(ctxb, wt_o, out0, Hdim, Hdim, Hdim, Hdim, Hdim, 1.f);
}